// Round 1
// baseline (1000.470 us; speedup 1.0000x reference)
//
#include <hip/hip_runtime.h>
#include <math.h>

#define DIM 256
#define NHEADS 8
#define HDIM 32
// (1/sqrt(256)) * log2(e)  -- folded into Q so scores are in exp2 domain
#define PREF 0.09016844005555896f
#define LEAKY 0.2f

// ---------------- zero ----------------
__global__ void zero_f32(float* __restrict__ p, int n) {
  int i = blockIdx.x * 256 + threadIdx.x;
  if (i < n) p[i] = 0.f;
}

// ---------------- QKV GEMM: [4096,256] @ [256,256] x3, fused into one grid ----------------
// grid (64, 12): blockIdx.y/4 selects W (Q,K,V), blockIdx.y%4 selects 64-col tile.
__global__ __launch_bounds__(256) void gemm_qkv(
    const float* __restrict__ A,
    const float* __restrict__ WQ, const float* __restrict__ WK, const float* __restrict__ WV,
    float* __restrict__ Qo, float* __restrict__ Ko, float* __restrict__ Vo) {
  __shared__ float As[16][68];   // [k][m], pad 68 -> 16B-aligned rows, low conflicts
  __shared__ float Bs[16][68];   // [k][n]
  const int tx = threadIdx.x & 15, ty = threadIdx.x >> 4;
  const int m0 = blockIdx.x * 64;
  const int wsel = blockIdx.y >> 2;
  const int n0 = (blockIdx.y & 3) * 64;
  const float* B = wsel == 0 ? WQ : (wsel == 1 ? WK : WV);
  float* C = wsel == 0 ? Qo : (wsel == 1 ? Ko : Vo);
  const int ar = threadIdx.x >> 2, ak = (threadIdx.x & 3) * 4;
  const int bk = threadIdx.x >> 4, bn = (threadIdx.x & 15) * 4;
  float acc[4][4] = {};
  for (int k0 = 0; k0 < DIM; k0 += 16) {
    float4 av = *(const float4*)&A[(m0 + ar) * DIM + k0 + ak];
    float4 bv = *(const float4*)&B[(k0 + bk) * DIM + n0 + bn];
    __syncthreads();                        // previous iter done reading LDS
    As[ak + 0][ar] = av.x; As[ak + 1][ar] = av.y;
    As[ak + 2][ar] = av.z; As[ak + 3][ar] = av.w;
    *(float4*)&Bs[bk][bn] = bv;
    __syncthreads();
#pragma unroll
    for (int k = 0; k < 16; ++k) {
      float4 a = *(const float4*)&As[k][ty * 4];
      float4 b = *(const float4*)&Bs[k][tx * 4];
      acc[0][0] = fmaf(a.x, b.x, acc[0][0]); acc[0][1] = fmaf(a.x, b.y, acc[0][1]);
      acc[0][2] = fmaf(a.x, b.z, acc[0][2]); acc[0][3] = fmaf(a.x, b.w, acc[0][3]);
      acc[1][0] = fmaf(a.y, b.x, acc[1][0]); acc[1][1] = fmaf(a.y, b.y, acc[1][1]);
      acc[1][2] = fmaf(a.y, b.z, acc[1][2]); acc[1][3] = fmaf(a.y, b.w, acc[1][3]);
      acc[2][0] = fmaf(a.z, b.x, acc[2][0]); acc[2][1] = fmaf(a.z, b.y, acc[2][1]);
      acc[2][2] = fmaf(a.z, b.z, acc[2][2]); acc[2][3] = fmaf(a.z, b.w, acc[2][3]);
      acc[3][0] = fmaf(a.w, b.x, acc[3][0]); acc[3][1] = fmaf(a.w, b.y, acc[3][1]);
      acc[3][2] = fmaf(a.w, b.z, acc[3][2]); acc[3][3] = fmaf(a.w, b.w, acc[3][3]);
    }
  }
#pragma unroll
  for (int i = 0; i < 4; ++i) {
    float4 o = make_float4(acc[i][0], acc[i][1], acc[i][2], acc[i][3]);
    *(float4*)&C[(m0 + ty * 4 + i) * DIM + n0 + tx * 4] = o;
  }
}

// ---------------- edge scatter: K2[dst] += K[src] ----------------
// one wave per edge (64 lanes x float4 = 256 channels)
__global__ void scatter_k2(const float* __restrict__ K, const int* __restrict__ src,
                           const int* __restrict__ dst, float* __restrict__ K2, int E) {
  int t = blockIdx.x * 256 + threadIdx.x;
  int e = t >> 6;
  if (e >= E) return;
  int c = (t & 63) * 4;
  int s = src[e], d = dst[e];
  float4 kv = *(const float4*)&K[s * DIM + c];
  float* o = &K2[d * DIM + c];
  atomicAdd(o + 0, kv.x); atomicAdd(o + 1, kv.y);
  atomicAdd(o + 2, kv.z); atomicAdd(o + 3, kv.w);
}

// ---------------- flash attention (fp32), writes H = inputs + attn ----------------
// grid (64 row-groups, 8 heads); block 256 = 4 waves.
// lane <-> row (64 rows/block); wave w owns key range [w*1024, w*1024+1024).
// No online max: scores are exp2-domain bounded (|s| <~ 25 at 6 sigma), fp32 range is ample,
// and key-split partials then merge by plain summation.
__global__ __launch_bounds__(256) void attn_flash(
    const float* __restrict__ Q, const float* __restrict__ K2,
    const float* __restrict__ V, const float* __restrict__ inp,
    float* __restrict__ H) {
  __shared__ float sbuf[9216];      // kt[4][32][36] | vt[4][32][36]; reused as merge[4][64][36]
  __shared__ float lbuf[4][64];
  const int lane = threadIdx.x & 63;
  const int w = threadIdx.x >> 6;
  const int h = blockIdx.y;
  const int row = blockIdx.x * 64 + lane;
  const int hc = h * HDIM;

  float q[32];
#pragma unroll
  for (int c4 = 0; c4 < 8; ++c4) {
    float4 qv = *(const float4*)&Q[row * DIM + hc + c4 * 4];
    q[c4 * 4 + 0] = qv.x * PREF; q[c4 * 4 + 1] = qv.y * PREF;
    q[c4 * 4 + 2] = qv.z * PREF; q[c4 * 4 + 3] = qv.w * PREF;
  }
  float o[32];
#pragma unroll
  for (int c = 0; c < 32; ++c) o[c] = 0.f;
  float l = 0.f;

  float* kt = &sbuf[w * 1152];
  float* vt = &sbuf[4608 + w * 1152];
  const int kk = lane >> 1;             // staging: 2 lanes per key
  const int coff = (lane & 1) * 16;

  for (int t = 0; t < 32; ++t) {        // 32 tiles x 32 keys = 1024 keys per wave
    const int kb = w * 1024 + t * 32;
    const float* kg = &K2[(kb + kk) * DIM + hc + coff];
    const float* vg = &V[(kb + kk) * DIM + hc + coff];
    float4 ka = *(const float4*)&kg[0];
    float4 kb4 = *(const float4*)&kg[4];
    float4 kc = *(const float4*)&kg[8];
    float4 kd4 = *(const float4*)&kg[12];
    float4 va = *(const float4*)&vg[0];
    float4 vb = *(const float4*)&vg[4];
    float4 vc = *(const float4*)&vg[8];
    float4 vd4 = *(const float4*)&vg[12];
    __syncthreads();
    float* kd = &kt[kk * 36 + coff];
    float* vd = &vt[kk * 36 + coff];
    *(float4*)&kd[0] = ka; *(float4*)&kd[4] = kb4;
    *(float4*)&kd[8] = kc; *(float4*)&kd[12] = kd4;
    *(float4*)&vd[0] = va; *(float4*)&vd[4] = vb;
    *(float4*)&vd[8] = vc; *(float4*)&vd[12] = vd4;
    __syncthreads();
#pragma unroll 2
    for (int jj = 0; jj < 32; ++jj) {
      const float* kr = &kt[jj * 36];
      float s = 0.f;
#pragma unroll
      for (int c4 = 0; c4 < 8; ++c4) {
        float4 kv = *(const float4*)&kr[c4 * 4];       // broadcast read
        s = fmaf(q[c4 * 4 + 0], kv.x, s);
        s = fmaf(q[c4 * 4 + 1], kv.y, s);
        s = fmaf(q[c4 * 4 + 2], kv.z, s);
        s = fmaf(q[c4 * 4 + 3], kv.w, s);
      }
      float p = exp2f(s);
      l += p;
      const float* vr = &vt[jj * 36];
#pragma unroll
      for (int c4 = 0; c4 < 8; ++c4) {
        float4 vv = *(const float4*)&vr[c4 * 4];       // broadcast read
        o[c4 * 4 + 0] = fmaf(p, vv.x, o[c4 * 4 + 0]);
        o[c4 * 4 + 1] = fmaf(p, vv.y, o[c4 * 4 + 1]);
        o[c4 * 4 + 2] = fmaf(p, vv.z, o[c4 * 4 + 2]);
        o[c4 * 4 + 3] = fmaf(p, vv.w, o[c4 * 4 + 3]);
      }
    }
  }

  // merge key-split partials through LDS (plain sums: no max tracking)
  __syncthreads();
  float* mo = &sbuf[w * 2304 + lane * 36];
#pragma unroll
  for (int c4 = 0; c4 < 8; ++c4)
    *(float4*)&mo[c4 * 4] = make_float4(o[c4 * 4 + 0], o[c4 * 4 + 1],
                                        o[c4 * 4 + 2], o[c4 * 4 + 3]);
  lbuf[w][lane] = l;
  __syncthreads();
  if (w == 0) {
    float ls = lbuf[0][lane] + lbuf[1][lane] + lbuf[2][lane] + lbuf[3][lane];
    float inv = 1.f / ls;
#pragma unroll
    for (int c4 = 0; c4 < 8; ++c4) {
      float4 a0 = *(const float4*)&sbuf[0 * 2304 + lane * 36 + c4 * 4];
      float4 a1 = *(const float4*)&sbuf[1 * 2304 + lane * 36 + c4 * 4];
      float4 a2 = *(const float4*)&sbuf[2 * 2304 + lane * 36 + c4 * 4];
      float4 a3 = *(const float4*)&sbuf[3 * 2304 + lane * 36 + c4 * 4];
      float4 iv = *(const float4*)&inp[row * DIM + hc + c4 * 4];
      float4 r;
      r.x = iv.x + (a0.x + a1.x + a2.x + a3.x) * inv;
      r.y = iv.y + (a0.y + a1.y + a2.y + a3.y) * inv;
      r.z = iv.z + (a0.z + a1.z + a2.z + a3.z) * inv;
      r.w = iv.w + (a0.w + a1.w + a2.w + a3.w) * inv;
      *(float4*)&H[row * DIM + hc + c4 * 4] = r;
    }
  }
}

// ---------------- final: out = H + leaky(H @ Wc + bc) ----------------
__global__ __launch_bounds__(256) void gemm_final(
    const float* __restrict__ Hbuf, const float* __restrict__ Wc,
    const float* __restrict__ bc, float* __restrict__ out) {
  __shared__ float As[16][68];
  __shared__ float Bs[16][68];
  const int tx = threadIdx.x & 15, ty = threadIdx.x >> 4;
  const int m0 = blockIdx.x * 64;
  const int n0 = blockIdx.y * 64;
  const int ar = threadIdx.x >> 2, ak = (threadIdx.x & 3) * 4;
  const int bk = threadIdx.x >> 4, bn = (threadIdx.x & 15) * 4;
  float acc[4][4] = {};
  for (int k0 = 0; k0 < DIM; k0 += 16) {
    float4 av = *(const float4*)&Hbuf[(m0 + ar) * DIM + k0 + ak];
    float4 bv = *(const float4*)&Wc[(k0 + bk) * DIM + n0 + bn];
    __syncthreads();
    As[ak + 0][ar] = av.x; As[ak + 1][ar] = av.y;
    As[ak + 2][ar] = av.z; As[ak + 3][ar] = av.w;
    *(float4*)&Bs[bk][bn] = bv;
    __syncthreads();
#pragma unroll
    for (int k = 0; k < 16; ++k) {
      float4 a = *(const float4*)&As[k][ty * 4];
      float4 b = *(const float4*)&Bs[k][tx * 4];
      acc[0][0] = fmaf(a.x, b.x, acc[0][0]); acc[0][1] = fmaf(a.x, b.y, acc[0][1]);
      acc[0][2] = fmaf(a.x, b.z, acc[0][2]); acc[0][3] = fmaf(a.x, b.w, acc[0][3]);
      acc[1][0] = fmaf(a.y, b.x, acc[1][0]); acc[1][1] = fmaf(a.y, b.y, acc[1][1]);
      acc[1][2] = fmaf(a.y, b.z, acc[1][2]); acc[1][3] = fmaf(a.y, b.w, acc[1][3]);
      acc[2][0] = fmaf(a.z, b.x, acc[2][0]); acc[2][1] = fmaf(a.z, b.y, acc[2][1]);
      acc[2][2] = fmaf(a.z, b.z, acc[2][2]); acc[2][3] = fmaf(a.z, b.w, acc[2][3]);
      acc[3][0] = fmaf(a.w, b.x, acc[3][0]); acc[3][1] = fmaf(a.w, b.y, acc[3][1]);
      acc[3][2] = fmaf(a.w, b.z, acc[3][2]); acc[3][3] = fmaf(a.w, b.w, acc[3][3]);
    }
  }
  float4 bcv = *(const float4*)&bc[n0 + tx * 4];
#pragma unroll
  for (int i = 0; i < 4; ++i) {
    float4 hv = *(const float4*)&Hbuf[(m0 + ty * 4 + i) * DIM + n0 + tx * 4];
    float x0 = acc[i][0] + bcv.x; x0 = x0 > 0.f ? x0 : LEAKY * x0;
    float x1 = acc[i][1] + bcv.y; x1 = x1 > 0.f ? x1 : LEAKY * x1;
    float x2 = acc[i][2] + bcv.z; x2 = x2 > 0.f ? x2 : LEAKY * x2;
    float x3 = acc[i][3] + bcv.w; x3 = x3 > 0.f ? x3 : LEAKY * x3;
    float4 r = make_float4(hv.x + x0, hv.y + x1, hv.z + x2, hv.w + x3);
    *(float4*)&out[(m0 + ty * 4 + i) * DIM + n0 + tx * 4] = r;
  }
}

extern "C" void kernel_launch(void* const* d_in, const int* in_sizes, int n_in,
                              void* d_out, int out_size, void* d_ws, size_t ws_size,
                              hipStream_t stream) {
  const float* inp = (const float*)d_in[0];
  const int* src   = (const int*)d_in[1];
  const int* dst   = (const int*)d_in[2];
  const float* WQ  = (const float*)d_in[3];
  const float* WK  = (const float*)d_in[4];
  const float* WV  = (const float*)d_in[5];
  const float* Wc  = (const float*)d_in[6];
  const float* bc  = (const float*)d_in[7];
  float* out = (float*)d_out;
  const int E = in_sizes[1];
  const int NM = 4096 * DIM;   // 1M floats per [N,D] buffer

  float* Q  = (float*)d_ws;    // ws layout: Q | K | V | K2 | H  (5 x 4MB = 20MB)
  float* K  = Q + NM;
  float* V  = K + NM;
  float* K2 = V + NM;
  float* Hb = K2 + NM;

  zero_f32<<<NM / 256, 256, 0, stream>>>(K2, NM);
  gemm_qkv<<<dim3(64, 12), 256, 0, stream>>>(inp, WQ, WK, WV, Q, K, V);
  scatter_k2<<<(E * 64 + 255) / 256, 256, 0, stream>>>(K, src, dst, K2, E);
  attn_flash<<<dim3(64, 8), 256, 0, stream>>>(Q, K2, V, inp, Hb);
  gemm_final<<<dim3(64, 4), 256, 0, stream>>>(Hb, Wc, bc, out);
}

// Round 2
// 238.276 us; speedup vs baseline: 4.1988x; 4.1988x over previous
//
#include <hip/hip_runtime.h>
#include <math.h>

#define DIM 256
#define HDIM 32
#define NN 4096
// (1/sqrt(256)) * log2(e) -- folded into Q so scores are in exp2 domain
#define PREF 0.09016844005555896f
#define LEAKY 0.2f

typedef __attribute__((ext_vector_type(8))) short short8;
typedef __attribute__((ext_vector_type(16))) float f32x16;

static __device__ __forceinline__ unsigned bfbits(float x) {
  unsigned u = __float_as_uint(x);
  return (u + 0x7fffu + ((u >> 16) & 1u)) >> 16;   // RNE f32->bf16 bits
}
static __device__ __forceinline__ float bf2f(unsigned short b) {
  return __uint_as_float(((unsigned)b) << 16);
}

// ---------------- zero ----------------
__global__ void zero_f32(float* __restrict__ p, int n) {
  int i = blockIdx.x * 256 + threadIdx.x;
  if (i < n) p[i] = 0.f;
}

// ---------------- QKV GEMM (fp32 compute): writes Q f32, K bf16, V^T bf16 ----------------
__global__ __launch_bounds__(256) void gemm_qkv(
    const float* __restrict__ A,
    const float* __restrict__ WQ, const float* __restrict__ WK, const float* __restrict__ WV,
    float* __restrict__ Qo, unsigned short* __restrict__ Kb, unsigned short* __restrict__ Vtb) {
  __shared__ float As[16][68];
  __shared__ float Bs[16][68];
  const int tx = threadIdx.x & 15, ty = threadIdx.x >> 4;
  const int m0 = blockIdx.x * 64;
  const int wsel = blockIdx.y >> 2;
  const int n0 = (blockIdx.y & 3) * 64;
  const float* B = wsel == 0 ? WQ : (wsel == 1 ? WK : WV);
  const int ar = threadIdx.x >> 2, ak = (threadIdx.x & 3) * 4;
  const int bk = threadIdx.x >> 4, bn = (threadIdx.x & 15) * 4;
  float acc[4][4] = {};
  for (int k0 = 0; k0 < DIM; k0 += 16) {
    float4 av = *(const float4*)&A[(m0 + ar) * DIM + k0 + ak];
    float4 bv = *(const float4*)&B[(k0 + bk) * DIM + n0 + bn];
    __syncthreads();
    As[ak + 0][ar] = av.x; As[ak + 1][ar] = av.y;
    As[ak + 2][ar] = av.z; As[ak + 3][ar] = av.w;
    *(float4*)&Bs[bk][bn] = bv;
    __syncthreads();
#pragma unroll
    for (int k = 0; k < 16; ++k) {
      float4 a = *(const float4*)&As[k][ty * 4];
      float4 b = *(const float4*)&Bs[k][tx * 4];
      acc[0][0] = fmaf(a.x, b.x, acc[0][0]); acc[0][1] = fmaf(a.x, b.y, acc[0][1]);
      acc[0][2] = fmaf(a.x, b.z, acc[0][2]); acc[0][3] = fmaf(a.x, b.w, acc[0][3]);
      acc[1][0] = fmaf(a.y, b.x, acc[1][0]); acc[1][1] = fmaf(a.y, b.y, acc[1][1]);
      acc[1][2] = fmaf(a.y, b.z, acc[1][2]); acc[1][3] = fmaf(a.y, b.w, acc[1][3]);
      acc[2][0] = fmaf(a.z, b.x, acc[2][0]); acc[2][1] = fmaf(a.z, b.y, acc[2][1]);
      acc[2][2] = fmaf(a.z, b.z, acc[2][2]); acc[2][3] = fmaf(a.z, b.w, acc[2][3]);
      acc[3][0] = fmaf(a.w, b.x, acc[3][0]); acc[3][1] = fmaf(a.w, b.y, acc[3][1]);
      acc[3][2] = fmaf(a.w, b.z, acc[3][2]); acc[3][3] = fmaf(a.w, b.w, acc[3][3]);
    }
  }
  if (wsel == 0) {
#pragma unroll
    for (int i = 0; i < 4; ++i)
      *(float4*)&Qo[(m0 + ty * 4 + i) * DIM + n0 + tx * 4] =
          make_float4(acc[i][0], acc[i][1], acc[i][2], acc[i][3]);
  } else if (wsel == 1) {
#pragma unroll
    for (int i = 0; i < 4; ++i) {
      ushort4 kv;
      kv.x = bfbits(acc[i][0]); kv.y = bfbits(acc[i][1]);
      kv.z = bfbits(acc[i][2]); kv.w = bfbits(acc[i][3]);
      *(ushort4*)&Kb[(m0 + ty * 4 + i) * DIM + n0 + tx * 4] = kv;
    }
  } else {
    // V^T: Vtb[dim][node], pack 4 bf16 along node (contiguous)
#pragma unroll
    for (int j = 0; j < 4; ++j) {
      ushort4 vv;
      vv.x = bfbits(acc[0][j]); vv.y = bfbits(acc[1][j]);
      vv.z = bfbits(acc[2][j]); vv.w = bfbits(acc[3][j]);
      *(ushort4*)&Vtb[(n0 + tx * 4 + j) * NN + m0 + ty * 4] = vv;
    }
  }
}

// ---------------- CSR build: histogram, scan, fill ----------------
__global__ void hist_dst(const int* __restrict__ dst, int* __restrict__ cnt, int E) {
  int e = blockIdx.x * 256 + threadIdx.x;
  if (e < E) atomicAdd(&cnt[dst[e]], 1);
}

__global__ void scan4096(const int* __restrict__ cnt, int* __restrict__ ofs,
                         int* __restrict__ cur) {
  __shared__ int ps[256];
  int t = threadIdx.x;
  int loc[16]; int s = 0;
#pragma unroll
  for (int i = 0; i < 16; ++i) { loc[i] = s; s += cnt[t * 16 + i]; }
  ps[t] = s;
  __syncthreads();
  for (int o = 1; o < 256; o <<= 1) {
    int v = ps[t];
    int u = (t >= o) ? ps[t - o] : 0;
    __syncthreads();
    ps[t] = v + u;
    __syncthreads();
  }
  int base = (t == 0) ? 0 : ps[t - 1];
#pragma unroll
  for (int i = 0; i < 16; ++i) {
    int v = base + loc[i];
    ofs[t * 16 + i] = v; cur[t * 16 + i] = v;
  }
  if (t == 255) ofs[4096] = ps[255];
}

__global__ void fill_edges(const int* __restrict__ src, const int* __restrict__ dst,
                           int* __restrict__ cur, int* __restrict__ esrc, int E) {
  int e = blockIdx.x * 256 + threadIdx.x;
  if (e < E) {
    int p = atomicAdd(&cur[dst[e]], 1);
    esrc[p] = src[e];
  }
}

// ---------------- K2 gather: wave per dst node, K2b[d] = sum K[src] (bf16 out) ----------------
__global__ __launch_bounds__(256) void gather_k2(
    const unsigned short* __restrict__ Kb, const int* __restrict__ ofs,
    const int* __restrict__ esrc, unsigned short* __restrict__ K2b) {
  int w = threadIdx.x >> 6, lane = threadIdx.x & 63;
  int d = blockIdx.x * 4 + w;
  int beg = ofs[d], end = ofs[d + 1];
  float a0 = 0, a1 = 0, a2 = 0, a3 = 0;
  for (int j = beg; j < end; ++j) {
    int s = esrc[j];
    ushort4 kv = *(const ushort4*)&Kb[s * DIM + lane * 4];
    a0 += bf2f(kv.x); a1 += bf2f(kv.y); a2 += bf2f(kv.z); a3 += bf2f(kv.w);
  }
  ushort4 o;
  o.x = bfbits(a0); o.y = bfbits(a1); o.z = bfbits(a2); o.w = bfbits(a3);
  *(ushort4*)&K2b[d * DIM + lane * 4] = o;
}

// ---------------- MFMA flash attention (bf16, 32x32x16) ----------------
// grid (32 q-blocks, 8 heads, 4 key-splits); block 256 = 4 waves, wave owns 32 q rows.
// Swapped form: S^T = mfma(A=K2, B=Q) -> lane holds 16 scores for ONE q (col = lane&31),
// keys (r&3)+8*(r>>2)+4*hi. P redistributed to PV B-frag via cvt_pk + v_permlane32_swap.
// O^T = mfma(A=V^T, B=P^T) accumulates 32 dims in one C-frag. No max-tracking (bounded exp2).
__global__ __launch_bounds__(256, 4) void attn_mfma(
    const float* __restrict__ Q, const unsigned short* __restrict__ K2b,
    const unsigned short* __restrict__ Vtb,
    float* __restrict__ Oacc, float* __restrict__ Lacc) {
  __shared__ __align__(16) short lk[128 * 40];   // [128 keys][32+8 pad] bf16, 80B rows
  __shared__ __align__(16) short lv[32 * 136];   // [32 dims][128+8 pad] bf16, 272B rows
  const int tid = threadIdx.x;
  const int lane = tid & 63;
  const int w = tid >> 6;
  const int kl = lane & 31;       // key-lane (QK A), q-lane (B/C), dim-lane (PV A)
  const int hi = lane >> 5;
  const int h = blockIdx.y, hc = h * HDIM;
  const int q = blockIdx.x * 128 + w * 32 + kl;
  const int ks0 = blockIdx.z * 1024;

  // Q B-frags: qf0 dims 0..15 (k = hi*8+j), qf1 dims 16..31. PREF folded.
  short8 qf0, qf1;
  {
    const float* qp = &Q[q * DIM + hc];
#pragma unroll
    for (int j = 0; j < 8; ++j) {
      ((unsigned short*)&qf0)[j] = (unsigned short)bfbits(qp[hi * 8 + j] * PREF);
      ((unsigned short*)&qf1)[j] = (unsigned short)bfbits(qp[16 + hi * 8 + j] * PREF);
    }
  }

  f32x16 o;
#pragma unroll
  for (int r = 0; r < 16; ++r) o[r] = 0.f;
  float lsum = 0.f;

  for (int t = 0; t < 8; ++t) {
    const int kb = ks0 + t * 128;
    short8 kreg0, kreg1, vreg0, vreg1;
    {
      int key = tid >> 2, slot = tid & 3;
      kreg0 = *(const short8*)&K2b[(kb + key) * DIM + hc + slot * 8];
      kreg1 = *(const short8*)&K2b[(kb + 64 + key) * DIM + hc + slot * 8];
      int dim = tid >> 3, s2 = tid & 7;
      vreg0 = *(const short8*)&Vtb[(hc + dim) * NN + kb + s2 * 8];
      vreg1 = *(const short8*)&Vtb[(hc + dim) * NN + kb + 64 + s2 * 8];
    }
    __syncthreads();
    {
      int key = tid >> 2, slot = tid & 3;
      *(short8*)&lk[key * 40 + slot * 8] = kreg0;
      *(short8*)&lk[(64 + key) * 40 + slot * 8] = kreg1;
      int dim = tid >> 3, s2 = tid & 7;
      *(short8*)&lv[dim * 136 + s2 * 8] = vreg0;
      *(short8*)&lv[dim * 136 + 64 + s2 * 8] = vreg1;
    }
    __syncthreads();

#pragma unroll
    for (int sub = 0; sub < 4; ++sub) {
      const int base = sub * 32;
      f32x16 c;
#pragma unroll
      for (int r = 0; r < 16; ++r) c[r] = 0.f;
      // QK^T (swapped): A = K2 rows (key = kl), two dim-halves accumulate
      short8 a0 = *(const short8*)&lk[(base + kl) * 40 + hi * 8];
      short8 a1 = *(const short8*)&lk[(base + kl) * 40 + 16 + hi * 8];
      c = __builtin_amdgcn_mfma_f32_32x32x16_bf16(a0, qf0, c, 0, 0, 0);
      c = __builtin_amdgcn_mfma_f32_32x32x16_bf16(a1, qf1, c, 0, 0, 0);
      float p[16];
#pragma unroll
      for (int r = 0; r < 16; ++r) { p[r] = exp2f(c[r]); lsum += p[r]; }
      // pack P pairs to bf16 words; permlane32_swap redistributes across hi halves
      unsigned X0 = bfbits(p[0]) | (bfbits(p[1]) << 16);
      unsigned Y0 = bfbits(p[2]) | (bfbits(p[3]) << 16);
      unsigned Z0 = bfbits(p[4]) | (bfbits(p[5]) << 16);
      unsigned W0 = bfbits(p[6]) | (bfbits(p[7]) << 16);
      asm volatile("v_permlane32_swap_b32 %0, %1" : "+v"(X0), "+v"(Z0));
      asm volatile("v_permlane32_swap_b32 %0, %1" : "+v"(Y0), "+v"(W0));
      unsigned X1 = bfbits(p[8]) | (bfbits(p[9]) << 16);
      unsigned Y1 = bfbits(p[10]) | (bfbits(p[11]) << 16);
      unsigned Z1 = bfbits(p[12]) | (bfbits(p[13]) << 16);
      unsigned W1 = bfbits(p[14]) | (bfbits(p[15]) << 16);
      asm volatile("v_permlane32_swap_b32 %0, %1" : "+v"(X1), "+v"(Z1));
      asm volatile("v_permlane32_swap_b32 %0, %1" : "+v"(Y1), "+v"(W1));
      short8 pb0, pb1;
      ((unsigned*)&pb0)[0] = X0; ((unsigned*)&pb0)[1] = Y0;
      ((unsigned*)&pb0)[2] = Z0; ((unsigned*)&pb0)[3] = W0;
      ((unsigned*)&pb1)[0] = X1; ((unsigned*)&pb1)[1] = Y1;
      ((unsigned*)&pb1)[2] = Z1; ((unsigned*)&pb1)[3] = W1;
      // PV: O^T += V^T @ P^T (two 16-key mfmas)
      short8 va0 = *(const short8*)&lv[kl * 136 + base + hi * 8];
      short8 va1 = *(const short8*)&lv[kl * 136 + base + 16 + hi * 8];
      o = __builtin_amdgcn_mfma_f32_32x32x16_bf16(va0, pb0, o, 0, 0, 0);
      o = __builtin_amdgcn_mfma_f32_32x32x16_bf16(va1, pb1, o, 0, 0, 0);
    }
  }

  float lt = lsum + __shfl_xor(lsum, 32);
#pragma unroll
  for (int r = 0; r < 16; ++r) {
    int d = (r & 3) + 8 * (r >> 2) + 4 * hi;
    atomicAdd(&Oacc[q * DIM + hc + d], o[r]);
  }
  if (hi == 0) atomicAdd(&Lacc[q * 8 + h], lt);
}

// ---------------- merge: H = inp + Oacc / Lacc ----------------
__global__ void merge_h(const float* __restrict__ inp, const float* __restrict__ Oacc,
                        const float* __restrict__ Lacc, float* __restrict__ H) {
  int i = (blockIdx.x * 256 + threadIdx.x) * 4;
  int q = i >> 8;
  int h = (i & 255) >> 5;
  float inv = 1.f / Lacc[q * 8 + h];
  float4 a = *(const float4*)&Oacc[i];
  float4 b = *(const float4*)&inp[i];
  *(float4*)&H[i] = make_float4(b.x + a.x * inv, b.y + a.y * inv,
                                b.z + a.z * inv, b.w + a.w * inv);
}

// ---------------- final: out = H + leaky(H @ Wc + bc) ----------------
__global__ __launch_bounds__(256) void gemm_final(
    const float* __restrict__ Hbuf, const float* __restrict__ Wc,
    const float* __restrict__ bc, float* __restrict__ out) {
  __shared__ float As[16][68];
  __shared__ float Bs[16][68];
  const int tx = threadIdx.x & 15, ty = threadIdx.x >> 4;
  const int m0 = blockIdx.x * 64;
  const int n0 = blockIdx.y * 64;
  const int ar = threadIdx.x >> 2, ak = (threadIdx.x & 3) * 4;
  const int bk = threadIdx.x >> 4, bn = (threadIdx.x & 15) * 4;
  float acc[4][4] = {};
  for (int k0 = 0; k0 < DIM; k0 += 16) {
    float4 av = *(const float4*)&Hbuf[(m0 + ar) * DIM + k0 + ak];
    float4 bv = *(const float4*)&Wc[(k0 + bk) * DIM + n0 + bn];
    __syncthreads();
    As[ak + 0][ar] = av.x; As[ak + 1][ar] = av.y;
    As[ak + 2][ar] = av.z; As[ak + 3][ar] = av.w;
    *(float4*)&Bs[bk][bn] = bv;
    __syncthreads();
#pragma unroll
    for (int k = 0; k < 16; ++k) {
      float4 a = *(const float4*)&As[k][ty * 4];
      float4 b = *(const float4*)&Bs[k][tx * 4];
      acc[0][0] = fmaf(a.x, b.x, acc[0][0]); acc[0][1] = fmaf(a.x, b.y, acc[0][1]);
      acc[0][2] = fmaf(a.x, b.z, acc[0][2]); acc[0][3] = fmaf(a.x, b.w, acc[0][3]);
      acc[1][0] = fmaf(a.y, b.x, acc[1][0]); acc[1][1] = fmaf(a.y, b.y, acc[1][1]);
      acc[1][2] = fmaf(a.y, b.z, acc[1][2]); acc[1][3] = fmaf(a.y, b.w, acc[1][3]);
      acc[2][0] = fmaf(a.z, b.x, acc[2][0]); acc[2][1] = fmaf(a.z, b.y, acc[2][1]);
      acc[2][2] = fmaf(a.z, b.z, acc[2][2]); acc[2][3] = fmaf(a.z, b.w, acc[2][3]);
      acc[3][0] = fmaf(a.w, b.x, acc[3][0]); acc[3][1] = fmaf(a.w, b.y, acc[3][1]);
      acc[3][2] = fmaf(a.w, b.z, acc[3][2]); acc[3][3] = fmaf(a.w, b.w, acc[3][3]);
    }
  }
  float4 bcv = *(const float4*)&bc[n0 + tx * 4];
#pragma unroll
  for (int i = 0; i < 4; ++i) {
    float4 hv = *(const float4*)&Hbuf[(m0 + ty * 4 + i) * DIM + n0 + tx * 4];
    float x0 = acc[i][0] + bcv.x; x0 = x0 > 0.f ? x0 : LEAKY * x0;
    float x1 = acc[i][1] + bcv.y; x1 = x1 > 0.f ? x1 : LEAKY * x1;
    float x2 = acc[i][2] + bcv.z; x2 = x2 > 0.f ? x2 : LEAKY * x2;
    float x3 = acc[i][3] + bcv.w; x3 = x3 > 0.f ? x3 : LEAKY * x3;
    *(float4*)&out[(m0 + ty * 4 + i) * DIM + n0 + tx * 4] =
        make_float4(hv.x + x0, hv.y + x1, hv.z + x2, hv.w + x3);
  }
}

extern "C" void kernel_launch(void* const* d_in, const int* in_sizes, int n_in,
                              void* d_out, int out_size, void* d_ws, size_t ws_size,
                              hipStream_t stream) {
  const float* inp = (const float*)d_in[0];
  const int* src   = (const int*)d_in[1];
  const int* dst   = (const int*)d_in[2];
  const float* WQ  = (const float*)d_in[3];
  const float* WK  = (const float*)d_in[4];
  const float* WV  = (const float*)d_in[5];
  const float* Wc  = (const float*)d_in[6];
  const float* bc  = (const float*)d_in[7];
  float* out = (float*)d_out;
  const int E = in_sizes[1];
  const int NM = NN * DIM;                 // 1M elements

  char* ws = (char*)d_ws;                  // ~18.8 MB total
  float* Q            = (float*)(ws + 0);                  // 4 MB
  unsigned short* Kb  = (unsigned short*)(ws + 4  * 1024 * 1024);  // 2 MB
  unsigned short* Vtb = (unsigned short*)(ws + 6  * 1024 * 1024);  // 2 MB
  unsigned short* K2b = (unsigned short*)(ws + 8  * 1024 * 1024);  // 2 MB
  float* Hb           = (float*)(ws + 10 * 1024 * 1024);   // 4 MB
  float* Oacc         = (float*)(ws + 14 * 1024 * 1024);   // 4 MB
  float* Lacc         = (float*)(ws + 18 * 1024 * 1024);   // 128 KB
  int* cnt            = (int*)(ws + 18 * 1024 * 1024 + 131072);    // 16 KB
  int* ofs            = (int*)(ws + 18 * 1024 * 1024 + 147456);    // 4097 ints
  int* cur            = (int*)(ws + 18 * 1024 * 1024 + 163856);    // 16 KB
  int* esrc           = (int*)(ws + 18 * 1024 * 1024 + 180240);    // 512 KB

  // zero Oacc + Lacc + cnt (contiguous region: 1M + 32K + 4K words)
  const int ZN = NM + NN * 8 + NN;
  zero_f32<<<(ZN + 255) / 256, 256, 0, stream>>>(Oacc, ZN);
  gemm_qkv<<<dim3(64, 12), 256, 0, stream>>>(inp, WQ, WK, WV, Q, Kb, Vtb);
  hist_dst<<<(E + 255) / 256, 256, 0, stream>>>(dst, cnt, E);
  scan4096<<<1, 256, 0, stream>>>(cnt, ofs, cur);
  fill_edges<<<(E + 255) / 256, 256, 0, stream>>>(src, dst, cur, esrc, E);
  gather_k2<<<NN / 4, 256, 0, stream>>>(Kb, ofs, esrc, K2b);
  attn_mfma<<<dim3(32, 8, 4), 256, 0, stream>>>(Q, K2b, Vtb, Oacc, Lacc);
  merge_h<<<NM / 1024, 256, 0, stream>>>(inp, Oacc, Lacc, Hb);
  gemm_final<<<dim3(64, 4), 256, 0, stream>>>(Hb, Wc, bc, out);
}

// Round 3
// 150.475 us; speedup vs baseline: 6.6487x; 1.5835x over previous
//
#include <hip/hip_runtime.h>
#include <hip/hip_bf16.h>
#include <math.h>

#define DIM 256
#define HDIM 32
#define NN 4096
#define NM (NN * DIM)
// (1/sqrt(256)) * log2(e) -- folded into Q so scores are in exp2 domain
#define PREF 0.09016844005555896f
#define LEAKY 0.2f

typedef __attribute__((ext_vector_type(8))) short short8;
typedef __attribute__((ext_vector_type(16))) float f32x16;

static __device__ __forceinline__ unsigned bfbits(float x) {
  unsigned u = __float_as_uint(x);
  return (u + 0x7fffu + ((u >> 16) & 1u)) >> 16;   // RNE f32->bf16 bits
}
static __device__ __forceinline__ float bf2f(unsigned short b) {
  return __uint_as_float(((unsigned)b) << 16);
}
static __device__ __forceinline__ unsigned pk_bf16(float lo, float hi) {
  __hip_bfloat162 t = __float22bfloat162_rn(make_float2(lo, hi));  // v_cvt_pk_bf16_f32
  return *(unsigned*)&t;
}

// ---------------- zero ----------------
__global__ void zero_i32(int* __restrict__ p, int n) {
  int i = blockIdx.x * 256 + threadIdx.x;
  if (i < n) p[i] = 0;
}

// ---------------- QKV GEMM (fp32 compute): writes Q f32, K bf16, V^T bf16 ----------------
__global__ __launch_bounds__(256) void gemm_qkv(
    const float* __restrict__ A,
    const float* __restrict__ WQ, const float* __restrict__ WK, const float* __restrict__ WV,
    float* __restrict__ Qo, unsigned short* __restrict__ Kb, unsigned short* __restrict__ Vtb) {
  __shared__ float As[16][68];
  __shared__ float Bs[16][68];
  const int tx = threadIdx.x & 15, ty = threadIdx.x >> 4;
  const int m0 = blockIdx.x * 64;
  const int wsel = blockIdx.y >> 2;
  const int n0 = (blockIdx.y & 3) * 64;
  const float* B = wsel == 0 ? WQ : (wsel == 1 ? WK : WV);
  const int ar = threadIdx.x >> 2, ak = (threadIdx.x & 3) * 4;
  const int bk = threadIdx.x >> 4, bn = (threadIdx.x & 15) * 4;
  float acc[4][4] = {};
  for (int k0 = 0; k0 < DIM; k0 += 16) {
    float4 av = *(const float4*)&A[(m0 + ar) * DIM + k0 + ak];
    float4 bv = *(const float4*)&B[(k0 + bk) * DIM + n0 + bn];
    __syncthreads();
    As[ak + 0][ar] = av.x; As[ak + 1][ar] = av.y;
    As[ak + 2][ar] = av.z; As[ak + 3][ar] = av.w;
    *(float4*)&Bs[bk][bn] = bv;
    __syncthreads();
#pragma unroll
    for (int k = 0; k < 16; ++k) {
      float4 a = *(const float4*)&As[k][ty * 4];
      float4 b = *(const float4*)&Bs[k][tx * 4];
      acc[0][0] = fmaf(a.x, b.x, acc[0][0]); acc[0][1] = fmaf(a.x, b.y, acc[0][1]);
      acc[0][2] = fmaf(a.x, b.z, acc[0][2]); acc[0][3] = fmaf(a.x, b.w, acc[0][3]);
      acc[1][0] = fmaf(a.y, b.x, acc[1][0]); acc[1][1] = fmaf(a.y, b.y, acc[1][1]);
      acc[1][2] = fmaf(a.y, b.z, acc[1][2]); acc[1][3] = fmaf(a.y, b.w, acc[1][3]);
      acc[2][0] = fmaf(a.z, b.x, acc[2][0]); acc[2][1] = fmaf(a.z, b.y, acc[2][1]);
      acc[2][2] = fmaf(a.z, b.z, acc[2][2]); acc[2][3] = fmaf(a.z, b.w, acc[2][3]);
      acc[3][0] = fmaf(a.w, b.x, acc[3][0]); acc[3][1] = fmaf(a.w, b.y, acc[3][1]);
      acc[3][2] = fmaf(a.w, b.z, acc[3][2]); acc[3][3] = fmaf(a.w, b.w, acc[3][3]);
    }
  }
  if (wsel == 0) {
#pragma unroll
    for (int i = 0; i < 4; ++i)
      *(float4*)&Qo[(m0 + ty * 4 + i) * DIM + n0 + tx * 4] =
          make_float4(acc[i][0], acc[i][1], acc[i][2], acc[i][3]);
  } else if (wsel == 1) {
#pragma unroll
    for (int i = 0; i < 4; ++i) {
      ushort4 kv;
      kv.x = bfbits(acc[i][0]); kv.y = bfbits(acc[i][1]);
      kv.z = bfbits(acc[i][2]); kv.w = bfbits(acc[i][3]);
      *(ushort4*)&Kb[(m0 + ty * 4 + i) * DIM + n0 + tx * 4] = kv;
    }
  } else {
    // V^T: Vtb[dim][node], pack 4 bf16 along node (contiguous)
#pragma unroll
    for (int j = 0; j < 4; ++j) {
      ushort4 vv;
      vv.x = bfbits(acc[0][j]); vv.y = bfbits(acc[1][j]);
      vv.z = bfbits(acc[2][j]); vv.w = bfbits(acc[3][j]);
      *(ushort4*)&Vtb[(n0 + tx * 4 + j) * NN + m0 + ty * 4] = vv;
    }
  }
}

// ---------------- CSR build: histogram, scan, fill ----------------
__global__ void hist_dst(const int* __restrict__ dst, int* __restrict__ cnt, int E) {
  int e = blockIdx.x * 256 + threadIdx.x;
  if (e < E) atomicAdd(&cnt[dst[e]], 1);
}

__global__ void scan4096(const int* __restrict__ cnt, int* __restrict__ ofs,
                         int* __restrict__ cur) {
  __shared__ int ps[256];
  int t = threadIdx.x;
  int loc[16]; int s = 0;
#pragma unroll
  for (int i = 0; i < 16; ++i) { loc[i] = s; s += cnt[t * 16 + i]; }
  ps[t] = s;
  __syncthreads();
  for (int o = 1; o < 256; o <<= 1) {
    int v = ps[t];
    int u = (t >= o) ? ps[t - o] : 0;
    __syncthreads();
    ps[t] = v + u;
    __syncthreads();
  }
  int base = (t == 0) ? 0 : ps[t - 1];
#pragma unroll
  for (int i = 0; i < 16; ++i) {
    int v = base + loc[i];
    ofs[t * 16 + i] = v; cur[t * 16 + i] = v;
  }
  if (t == 255) ofs[4096] = ps[255];
}

__global__ void fill_edges(const int* __restrict__ src, const int* __restrict__ dst,
                           int* __restrict__ cur, int* __restrict__ esrc, int E) {
  int e = blockIdx.x * 256 + threadIdx.x;
  if (e < E) {
    int p = atomicAdd(&cur[dst[e]], 1);
    esrc[p] = src[e];
  }
}

// ---------------- K2 gather: wave per dst node, K2b[d] = sum K[src] (bf16 out) ----------------
__global__ __launch_bounds__(256) void gather_k2(
    const unsigned short* __restrict__ Kb, const int* __restrict__ ofs,
    const int* __restrict__ esrc, unsigned short* __restrict__ K2b) {
  int w = threadIdx.x >> 6, lane = threadIdx.x & 63;
  int d = blockIdx.x * 4 + w;
  int beg = ofs[d], end = ofs[d + 1];
  float a0 = 0, a1 = 0, a2 = 0, a3 = 0;
  for (int j = beg; j < end; ++j) {
    int s = esrc[j];
    ushort4 kv = *(const ushort4*)&Kb[s * DIM + lane * 4];
    a0 += bf2f(kv.x); a1 += bf2f(kv.y); a2 += bf2f(kv.z); a3 += bf2f(kv.w);
  }
  ushort4 o;
  o.x = bfbits(a0); o.y = bfbits(a1); o.z = bfbits(a2); o.w = bfbits(a3);
  *(ushort4*)&K2b[d * DIM + lane * 4] = o;
}

// ---------------- MFMA flash attention (bf16, 32x32x16) ----------------
// grid (32 q-blocks, 8 heads, 4 key-splits); block 256 = 4 waves, wave owns 32 q rows.
// Swapped form: S^T = mfma(A=K2, B=Q) -> lane holds 16 scores for ONE q (col = lane&31).
// P redistributed to PV B-frag via cvt_pk + v_permlane32_swap (T12).
// O^T = mfma(A=V^T, B=P^T). No max-tracking (bounded exp2-domain scores).
// Partials: plain coalesced stores to OT[z][dim][q] + Lp[z][h][q] -- NO atomics
// (round-2 lesson: device-scope fp atomics bypass L2 -> 70 MB HBM RMW traffic).
__global__ __launch_bounds__(256, 4) void attn_mfma(
    const float* __restrict__ Q, const unsigned short* __restrict__ K2b,
    const unsigned short* __restrict__ Vtb,
    float* __restrict__ OT, float* __restrict__ Lp) {
  __shared__ __align__(16) short lk[128 * 40];   // [128 keys][32+8 pad] bf16, 80B rows
  __shared__ __align__(16) short lv[32 * 136];   // [32 dims][128+8 pad] bf16, 272B rows
  const int tid = threadIdx.x;
  const int lane = tid & 63;
  const int w = tid >> 6;
  const int kl = lane & 31;       // key-lane (QK A), q-lane (B/C), dim-lane (PV A)
  const int hi = lane >> 5;
  const int h = blockIdx.y, hc = h * HDIM;
  const int q = blockIdx.x * 128 + w * 32 + kl;
  const int ks0 = blockIdx.z * 1024;

  // Q B-frags: qf0 dims 0..15 (k = hi*8+j), qf1 dims 16..31. PREF folded.
  short8 qf0, qf1;
  {
    const float* qp = &Q[q * DIM + hc];
#pragma unroll
    for (int j = 0; j < 8; ++j) {
      ((unsigned short*)&qf0)[j] = (unsigned short)bfbits(qp[hi * 8 + j] * PREF);
      ((unsigned short*)&qf1)[j] = (unsigned short)bfbits(qp[16 + hi * 8 + j] * PREF);
    }
  }

  f32x16 o;
#pragma unroll
  for (int r = 0; r < 16; ++r) o[r] = 0.f;
  float lsum = 0.f;

  for (int t = 0; t < 8; ++t) {
    const int kb = ks0 + t * 128;
    short8 kreg0, kreg1, vreg0, vreg1;
    {
      int key = tid >> 2, slot = tid & 3;
      kreg0 = *(const short8*)&K2b[(kb + key) * DIM + hc + slot * 8];
      kreg1 = *(const short8*)&K2b[(kb + 64 + key) * DIM + hc + slot * 8];
      int dim = tid >> 3, s2 = tid & 7;
      vreg0 = *(const short8*)&Vtb[(hc + dim) * NN + kb + s2 * 8];
      vreg1 = *(const short8*)&Vtb[(hc + dim) * NN + kb + 64 + s2 * 8];
    }
    __syncthreads();
    {
      int key = tid >> 2, slot = tid & 3;
      *(short8*)&lk[key * 40 + slot * 8] = kreg0;
      *(short8*)&lk[(64 + key) * 40 + slot * 8] = kreg1;
      int dim = tid >> 3, s2 = tid & 7;
      *(short8*)&lv[dim * 136 + s2 * 8] = vreg0;
      *(short8*)&lv[dim * 136 + 64 + s2 * 8] = vreg1;
    }
    __syncthreads();

#pragma unroll
    for (int sub = 0; sub < 4; ++sub) {
      const int base = sub * 32;
      f32x16 c;
#pragma unroll
      for (int r = 0; r < 16; ++r) c[r] = 0.f;
      // QK^T (swapped): A = K2 rows (key = kl), two dim-halves accumulate
      short8 a0 = *(const short8*)&lk[(base + kl) * 40 + hi * 8];
      short8 a1 = *(const short8*)&lk[(base + kl) * 40 + 16 + hi * 8];
      c = __builtin_amdgcn_mfma_f32_32x32x16_bf16(a0, qf0, c, 0, 0, 0);
      c = __builtin_amdgcn_mfma_f32_32x32x16_bf16(a1, qf1, c, 0, 0, 0);
      float p[16];
#pragma unroll
      for (int r = 0; r < 16; ++r) { p[r] = exp2f(c[r]); lsum += p[r]; }
      // pack P pairs to bf16 words (cvt_pk); permlane32_swap redistributes hi halves
      unsigned X0 = pk_bf16(p[0], p[1]);
      unsigned Y0 = pk_bf16(p[2], p[3]);
      unsigned Z0 = pk_bf16(p[4], p[5]);
      unsigned W0 = pk_bf16(p[6], p[7]);
      asm volatile("v_permlane32_swap_b32 %0, %1" : "+v"(X0), "+v"(Z0));
      asm volatile("v_permlane32_swap_b32 %0, %1" : "+v"(Y0), "+v"(W0));
      unsigned X1 = pk_bf16(p[8], p[9]);
      unsigned Y1 = pk_bf16(p[10], p[11]);
      unsigned Z1 = pk_bf16(p[12], p[13]);
      unsigned W1 = pk_bf16(p[14], p[15]);
      asm volatile("v_permlane32_swap_b32 %0, %1" : "+v"(X1), "+v"(Z1));
      asm volatile("v_permlane32_swap_b32 %0, %1" : "+v"(Y1), "+v"(W1));
      short8 pb0, pb1;
      ((unsigned*)&pb0)[0] = X0; ((unsigned*)&pb0)[1] = Y0;
      ((unsigned*)&pb0)[2] = Z0; ((unsigned*)&pb0)[3] = W0;
      ((unsigned*)&pb1)[0] = X1; ((unsigned*)&pb1)[1] = Y1;
      ((unsigned*)&pb1)[2] = Z1; ((unsigned*)&pb1)[3] = W1;
      // PV: O^T += V^T @ P^T (two 16-key mfmas)
      short8 va0 = *(const short8*)&lv[kl * 136 + base + hi * 8];
      short8 va1 = *(const short8*)&lv[kl * 136 + base + 16 + hi * 8];
      o = __builtin_amdgcn_mfma_f32_32x32x16_bf16(va0, pb0, o, 0, 0, 0);
      o = __builtin_amdgcn_mfma_f32_32x32x16_bf16(va1, pb1, o, 0, 0, 0);
    }
  }

  // coalesced partial stores (O^T frag: col = q, row = dim)
  float lt = lsum + __shfl_xor(lsum, 32);
  float* OTz = OT + blockIdx.z * NM;
#pragma unroll
  for (int r = 0; r < 16; ++r) {
    int d = (r & 3) + 8 * (r >> 2) + 4 * hi;
    OTz[(hc + d) * NN + q] = o[r];
  }
  if (hi == 0) Lp[(blockIdx.z * 8 + h) * NN + q] = lt;
}

// ---------------- merge: H = inp + (sum_z OT_z)^T / (sum_z Lp_z) ----------------
// grid (32 q-blocks, 8 heads); block handles 128 q x 32 dims, LDS transpose.
__global__ __launch_bounds__(256) void merge_h(
    const float* __restrict__ inp, const float* __restrict__ OT,
    const float* __restrict__ Lp, float* __restrict__ H) {
  __shared__ float ls[32][132];
  __shared__ float linv[128];
  const int tid = threadIdx.x;
  const int qb = blockIdx.x * 128;
  const int h = blockIdx.y, hc = h * HDIM;

#pragma unroll
  for (int pass = 0; pass < 4; ++pass) {
    int d = (tid >> 5) + pass * 8;
    int q4 = (tid & 31) * 4;
    const float* p0 = &OT[(hc + d) * NN + qb + q4];
    float4 a = *(const float4*)&p0[0];
    float4 b = *(const float4*)&p0[NM];
    float4 c = *(const float4*)&p0[2 * NM];
    float4 e = *(const float4*)&p0[3 * NM];
    ls[d][q4 + 0] = a.x + b.x + c.x + e.x;
    ls[d][q4 + 1] = a.y + b.y + c.y + e.y;
    ls[d][q4 + 2] = a.z + b.z + c.z + e.z;
    ls[d][q4 + 3] = a.w + b.w + c.w + e.w;
  }
  if (tid < 128) {
    int q = qb + tid;
    linv[tid] = 1.f / (Lp[h * NN + q] + Lp[(8 + h) * NN + q] +
                       Lp[(16 + h) * NN + q] + Lp[(24 + h) * NN + q]);
  }
  __syncthreads();
#pragma unroll
  for (int pass = 0; pass < 4; ++pass) {
    int q = (tid >> 3) + pass * 32;
    int dg = (tid & 7) * 4;
    float iv = linv[q];
    const float* ip = &inp[(qb + q) * DIM + hc + dg];
    float4 in4 = *(const float4*)ip;
    float4 r;
    r.x = in4.x + ls[dg + 0][q] * iv;
    r.y = in4.y + ls[dg + 1][q] * iv;
    r.z = in4.z + ls[dg + 2][q] * iv;
    r.w = in4.w + ls[dg + 3][q] * iv;
    *(float4*)&H[(qb + q) * DIM + hc + dg] = r;
  }
}

// ---------------- final: out = H + leaky(H @ Wc + bc) ----------------
__global__ __launch_bounds__(256) void gemm_final(
    const float* __restrict__ Hbuf, const float* __restrict__ Wc,
    const float* __restrict__ bc, float* __restrict__ out) {
  __shared__ float As[16][68];
  __shared__ float Bs[16][68];
  const int tx = threadIdx.x & 15, ty = threadIdx.x >> 4;
  const int m0 = blockIdx.x * 64;
  const int n0 = blockIdx.y * 64;
  const int ar = threadIdx.x >> 2, ak = (threadIdx.x & 3) * 4;
  const int bk = threadIdx.x >> 4, bn = (threadIdx.x & 15) * 4;
  float acc[4][4] = {};
  for (int k0 = 0; k0 < DIM; k0 += 16) {
    float4 av = *(const float4*)&Hbuf[(m0 + ar) * DIM + k0 + ak];
    float4 bv = *(const float4*)&Wc[(k0 + bk) * DIM + n0 + bn];
    __syncthreads();
    As[ak + 0][ar] = av.x; As[ak + 1][ar] = av.y;
    As[ak + 2][ar] = av.z; As[ak + 3][ar] = av.w;
    *(float4*)&Bs[bk][bn] = bv;
    __syncthreads();
#pragma unroll
    for (int k = 0; k < 16; ++k) {
      float4 a = *(const float4*)&As[k][ty * 4];
      float4 b = *(const float4*)&Bs[k][tx * 4];
      acc[0][0] = fmaf(a.x, b.x, acc[0][0]); acc[0][1] = fmaf(a.x, b.y, acc[0][1]);
      acc[0][2] = fmaf(a.x, b.z, acc[0][2]); acc[0][3] = fmaf(a.x, b.w, acc[0][3]);
      acc[1][0] = fmaf(a.y, b.x, acc[1][0]); acc[1][1] = fmaf(a.y, b.y, acc[1][1]);
      acc[1][2] = fmaf(a.y, b.z, acc[1][2]); acc[1][3] = fmaf(a.y, b.w, acc[1][3]);
      acc[2][0] = fmaf(a.z, b.x, acc[2][0]); acc[2][1] = fmaf(a.z, b.y, acc[2][1]);
      acc[2][2] = fmaf(a.z, b.z, acc[2][2]); acc[2][3] = fmaf(a.z, b.w, acc[2][3]);
      acc[3][0] = fmaf(a.w, b.x, acc[3][0]); acc[3][1] = fmaf(a.w, b.y, acc[3][1]);
      acc[3][2] = fmaf(a.w, b.z, acc[3][2]); acc[3][3] = fmaf(a.w, b.w, acc[3][3]);
    }
  }
  float4 bcv = *(const float4*)&bc[n0 + tx * 4];
#pragma unroll
  for (int i = 0; i < 4; ++i) {
    float4 hv = *(const float4*)&Hbuf[(m0 + ty * 4 + i) * DIM + n0 + tx * 4];
    float x0 = acc[i][0] + bcv.x; x0 = x0 > 0.f ? x0 : LEAKY * x0;
    float x1 = acc[i][1] + bcv.y; x1 = x1 > 0.f ? x1 : LEAKY * x1;
    float x2 = acc[i][2] + bcv.z; x2 = x2 > 0.f ? x2 : LEAKY * x2;
    float x3 = acc[i][3] + bcv.w; x3 = x3 > 0.f ? x3 : LEAKY * x3;
    *(float4*)&out[(m0 + ty * 4 + i) * DIM + n0 + tx * 4] =
        make_float4(hv.x + x0, hv.y + x1, hv.z + x2, hv.w + x3);
  }
}

extern "C" void kernel_launch(void* const* d_in, const int* in_sizes, int n_in,
                              void* d_out, int out_size, void* d_ws, size_t ws_size,
                              hipStream_t stream) {
  const float* inp = (const float*)d_in[0];
  const int* src   = (const int*)d_in[1];
  const int* dst   = (const int*)d_in[2];
  const float* WQ  = (const float*)d_in[3];
  const float* WK  = (const float*)d_in[4];
  const float* WV  = (const float*)d_in[5];
  const float* Wc  = (const float*)d_in[6];
  const float* bc  = (const float*)d_in[7];
  float* out = (float*)d_out;
  const int E = in_sizes[1];

  char* ws = (char*)d_ws;                  // ~27.6 MB total
  float* Q            = (float*)(ws + 0);                          // 4 MB (reused as H)
  unsigned short* Kb  = (unsigned short*)(ws + 4  * 1024 * 1024);  // 2 MB
  unsigned short* Vtb = (unsigned short*)(ws + 6  * 1024 * 1024);  // 2 MB
  unsigned short* K2b = (unsigned short*)(ws + 8  * 1024 * 1024);  // 2 MB
  float* OT           = (float*)(ws + 10 * 1024 * 1024);           // 16 MB (4 x [256][4096])
  float* Lp           = (float*)(ws + 26 * 1024 * 1024);           // 512 KB (4 x [8][4096])
  char* csr           = ws + 26 * 1024 * 1024 + 524288;
  int* cnt            = (int*)(csr);                // 16 KB
  int* ofs            = (int*)(csr + 16384);        // 16.4 KB
  int* cur            = (int*)(csr + 36864);        // 16 KB
  int* esrc           = (int*)(csr + 53248);        // 512 KB
  float* Hb = Q;   // Q dead after attn_mfma; merge_h writes H there

  zero_i32<<<16, 256, 0, stream>>>(cnt, NN);
  gemm_qkv<<<dim3(64, 12), 256, 0, stream>>>(inp, WQ, WK, WV, Q, Kb, Vtb);
  hist_dst<<<(E + 255) / 256, 256, 0, stream>>>(dst, cnt, E);
  scan4096<<<1, 256, 0, stream>>>(cnt, ofs, cur);
  fill_edges<<<(E + 255) / 256, 256, 0, stream>>>(src, dst, cur, esrc, E);
  gather_k2<<<NN / 4, 256, 0, stream>>>(Kb, ofs, esrc, K2b);
  attn_mfma<<<dim3(32, 8, 4), 256, 0, stream>>>(Q, K2b, Vtb, OT, Lp);
  merge_h<<<dim3(32, 8), 256, 0, stream>>>(inp, OT, Lp, Hb);
  gemm_final<<<dim3(64, 4), 256, 0, stream>>>(Hb, Wc, bc, out);
}

// Round 5
// 110.776 us; speedup vs baseline: 9.0315x; 1.3584x over previous
//
#include <hip/hip_runtime.h>
#include <hip/hip_bf16.h>
#include <math.h>

#define DIM 256
#define HDIM 32
#define NN 4096
#define NM (NN * DIM)
// (1/sqrt(256)) * log2(e) -- folded into WQ so scores are in exp2 domain
#define PREF 0.09016844005555896f
#define LEAKY 0.2f

typedef __attribute__((ext_vector_type(8))) short short8;
typedef __attribute__((ext_vector_type(16))) float f32x16;

#if __has_builtin(__builtin_amdgcn_exp2f)
#define EXP2(x) __builtin_amdgcn_exp2f(x)   // raw v_exp_f32: scores bounded, no fixups needed
#else
#define EXP2(x) exp2f(x)
#endif

static __device__ __forceinline__ unsigned bfbits(float x) {
  unsigned u = __float_as_uint(x);
  return (u + 0x7fffu + ((u >> 16) & 1u)) >> 16;   // RNE f32->bf16 bits
}
static __device__ __forceinline__ float bf2f(unsigned short b) {
  return __uint_as_float(((unsigned)b) << 16);
}
static __device__ __forceinline__ unsigned pk_bf16(float lo, float hi) {
  __hip_bfloat162 t = __float22bfloat162_rn(make_float2(lo, hi));  // v_cvt_pk_bf16_f32
  return *(unsigned*)&t;
}

// ---------------- zero ----------------
__global__ void zero_i32(int* __restrict__ p, int n) {
  int i = blockIdx.x * 256 + threadIdx.x;
  if (i < n) p[i] = 0;
}

// ---------------- weight convert: Wtb[w][n][k] = bf16(W_w[k][n] * scale_w) ----------------
// grid (16 tiles, 4 w). PREF folded into WQ (w==0).
__global__ __launch_bounds__(256) void convert_w(
    const float* __restrict__ W0, const float* __restrict__ W1,
    const float* __restrict__ W2, const float* __restrict__ W3,
    unsigned short* __restrict__ Wtb) {
  __shared__ float tile[64][68];
  const int wsel = blockIdx.y;
  const float* W = wsel == 0 ? W0 : (wsel == 1 ? W1 : (wsel == 2 ? W2 : W3));
  const float scale = wsel == 0 ? PREF : 1.f;
  const int kb = (blockIdx.x & 3) * 64, nb = (blockIdx.x >> 2) * 64;
  const int tid = threadIdx.x;
#pragma unroll
  for (int i = 0; i < 4; ++i) {
    int idx = i * 256 + tid;                 // [0,1024)
    int kr = idx >> 4, ns = idx & 15;
    float4 v = *(const float4*)&W[(kb + kr) * DIM + nb + ns * 4];
    tile[kr][ns * 4 + 0] = v.x; tile[kr][ns * 4 + 1] = v.y;
    tile[kr][ns * 4 + 2] = v.z; tile[kr][ns * 4 + 3] = v.w;
  }
  __syncthreads();
  unsigned short* o = Wtb + wsel * 65536;
#pragma unroll
  for (int i = 0; i < 2; ++i) {
    int idx = i * 256 + tid;                 // [0,512) = 64 n-rows x 8 kslots
    int nr = idx >> 3, kslot = idx & 7;
    short8 v;
#pragma unroll
    for (int j = 0; j < 8; ++j)
      ((unsigned short*)&v)[j] = (unsigned short)bfbits(tile[kslot * 8 + j][nr] * scale);
    *(short8*)&o[(nb + nr) * DIM + kb + kslot * 8] = v;
  }
}

// ---------------- QKV GEMM (bf16 MFMA 32x32x16): C = inp @ W, out bf16 row-major ----------
// grid (64 mtiles, 4 ntiles, 3 wsel). Block 256 = 4 waves in 2x2 over 64x64 tile.
// LDS rows 512B (=256 bf16, full K), XOR-swizzle byte ^= ((row&15)<<4).
__global__ __launch_bounds__(256) void gemm_qkv_mfma(
    const float* __restrict__ A, const unsigned short* __restrict__ Wtb,
    unsigned short* __restrict__ Qb, unsigned short* __restrict__ Kb,
    unsigned short* __restrict__ Vb) {
  __shared__ __align__(16) short sA[64 * 256];   // 32 KB
  __shared__ __align__(16) short sB[64 * 256];   // 32 KB
  const int tid = threadIdx.x;
  const int m0 = blockIdx.x * 64;
  const int n0 = blockIdx.y * 64;
  const int wsel = blockIdx.z;
  const unsigned short* Wt = Wtb + wsel * 65536;
  // stage A: f32 -> bf16 during copy. 64 rows x 64 slots x 4 f32 = full 64x256.
#pragma unroll
  for (int i = 0; i < 16; ++i) {
    int idx = i * 256 + tid;                 // [0,4096)
    int row = idx >> 6, slot = idx & 63;
    float4 v = *(const float4*)&A[(m0 + row) * DIM + slot * 4];
    uint2 pk = make_uint2(pk_bf16(v.x, v.y), pk_bf16(v.z, v.w));
    int byte = (slot * 8) ^ ((row & 15) << 4);
    *(uint2*)((char*)sA + row * 512 + byte) = pk;
  }
  // stage B: 64 rows x 32 slots x 16B = full 64x256 bf16 (r4 BUG: was 16 slots = half K)
#pragma unroll
  for (int i = 0; i < 8; ++i) {
    int idx = i * 256 + tid;                 // [0,2048)
    int row = idx >> 5, slot = idx & 31;
    short8 v = *(const short8*)&Wt[(n0 + row) * DIM + slot * 8];
    int byte = (slot * 16) ^ ((row & 15) << 4);
    *(short8*)((char*)sB + row * 512 + byte) = v;
  }
  __syncthreads();
  const int kl = tid & 31, hi = (tid & 63) >> 5, w = tid >> 6;
  const int rw = (w >> 1) * 32, cw = (w & 1) * 32;
  const int arow = rw + kl, brow = cw + kl;
  const int axor = (arow & 15) << 4, bxor = (brow & 15) << 4;
  const char* apA = (const char*)sA + arow * 512;
  const char* apB = (const char*)sB + brow * 512;
  f32x16 acc;
#pragma unroll
  for (int r = 0; r < 16; ++r) acc[r] = 0.f;
#pragma unroll
  for (int ks = 0; ks < 16; ++ks) {
    int cb = ks * 32 + hi * 16;
    short8 a = *(const short8*)(apA + (cb ^ axor));
    short8 b = *(const short8*)(apB + (cb ^ bxor));
    acc = __builtin_amdgcn_mfma_f32_32x32x16_bf16(a, b, acc, 0, 0, 0);
  }
  unsigned short* C = wsel == 0 ? Qb : (wsel == 1 ? Kb : Vb);
#pragma unroll
  for (int r = 0; r < 16; ++r) {
    int mrow = (r & 3) + 8 * (r >> 2) + 4 * hi;
    C[(m0 + rw + mrow) * DIM + n0 + cw + kl] = (unsigned short)bfbits(acc[r]);
  }
}

// ---------------- V transpose: Vtb[dim][node] = Vb[node][dim] ----------------
__global__ __launch_bounds__(256) void transpose_v(
    const unsigned short* __restrict__ Vb, unsigned short* __restrict__ Vtb) {
  __shared__ __align__(16) unsigned short tile[64][72];
  const int nb = blockIdx.x * 64;
  const int db = blockIdx.y * 64;
  const int tid = threadIdx.x;
#pragma unroll
  for (int i = 0; i < 2; ++i) {
    int idx = i * 256 + tid;                 // [0,512) = 64 nodes x 8 slots x 8 dims
    int row = idx >> 3, slot = idx & 7;
    short8 v = *(const short8*)&Vb[(nb + row) * DIM + db + slot * 8];
    *(short8*)&tile[row][slot * 8] = v;      // 144B rows (9x16B), 16B-aligned
  }
  __syncthreads();
#pragma unroll
  for (int i = 0; i < 2; ++i) {
    int idx = i * 256 + tid;
    int drow = idx >> 3, nslot = idx & 7;
    short8 v;
#pragma unroll
    for (int j = 0; j < 8; ++j) ((unsigned short*)&v)[j] = tile[nslot * 8 + j][drow];
    *(short8*)&Vtb[(db + drow) * NN + nb + nslot * 8] = v;
  }
}

// ---------------- CSR build: histogram, scan, fill ----------------
__global__ void hist_dst(const int* __restrict__ dst, int* __restrict__ cnt, int E) {
  int e = blockIdx.x * 256 + threadIdx.x;
  if (e < E) atomicAdd(&cnt[dst[e]], 1);
}

__global__ void scan4096(const int* __restrict__ cnt, int* __restrict__ ofs,
                         int* __restrict__ cur) {
  __shared__ int ps[256];
  int t = threadIdx.x;
  int loc[16]; int s = 0;
#pragma unroll
  for (int i = 0; i < 16; ++i) { loc[i] = s; s += cnt[t * 16 + i]; }
  ps[t] = s;
  __syncthreads();
  for (int o = 1; o < 256; o <<= 1) {
    int v = ps[t];
    int u = (t >= o) ? ps[t - o] : 0;
    __syncthreads();
    ps[t] = v + u;
    __syncthreads();
  }
  int base = (t == 0) ? 0 : ps[t - 1];
#pragma unroll
  for (int i = 0; i < 16; ++i) {
    int v = base + loc[i];
    ofs[t * 16 + i] = v; cur[t * 16 + i] = v;
  }
  if (t == 255) ofs[4096] = ps[255];
}

__global__ void fill_edges(const int* __restrict__ src, const int* __restrict__ dst,
                           int* __restrict__ cur, int* __restrict__ esrc, int E) {
  int e = blockIdx.x * 256 + threadIdx.x;
  if (e < E) {
    int p = atomicAdd(&cur[dst[e]], 1);
    esrc[p] = src[e];
  }
}

// ---------------- K2 gather: wave per dst node, K2b[d] = sum K[src] (bf16 out) ----------------
__global__ __launch_bounds__(256) void gather_k2(
    const unsigned short* __restrict__ Kb, const int* __restrict__ ofs,
    const int* __restrict__ esrc, unsigned short* __restrict__ K2b) {
  int w = threadIdx.x >> 6, lane = threadIdx.x & 63;
  int d = blockIdx.x * 4 + w;
  int beg = ofs[d], end = ofs[d + 1];
  float a0 = 0, a1 = 0, a2 = 0, a3 = 0;
  for (int j = beg; j < end; ++j) {
    int s = esrc[j];
    ushort4 kv = *(const ushort4*)&Kb[s * DIM + lane * 4];
    a0 += bf2f(kv.x); a1 += bf2f(kv.y); a2 += bf2f(kv.z); a3 += bf2f(kv.w);
  }
  ushort4 o;
  o.x = bfbits(a0); o.y = bfbits(a1); o.z = bfbits(a2); o.w = bfbits(a3);
  *(ushort4*)&K2b[d * DIM + lane * 4] = o;
}

// ---------------- MFMA flash attention (bf16, 32x32x16) ----------------
// grid (32 q-blocks, 8 heads, 8 key-splits); block 256 = 4 waves, wave owns 32 q rows.
// Swapped form: S^T = mfma(A=K2, B=Q); P redistributed via cvt_pk + permlane32_swap (T12);
// O^T = mfma(A=V^T, B=P^T). No max-tracking (bounded exp2-domain scores).
__global__ __launch_bounds__(256, 4) void attn_mfma(
    const unsigned short* __restrict__ Qb, const unsigned short* __restrict__ K2b,
    const unsigned short* __restrict__ Vtb,
    unsigned short* __restrict__ OT, float* __restrict__ Lp) {
  __shared__ __align__(16) short lk[128 * 40];   // [128 keys][32+8 pad] bf16
  __shared__ __align__(16) short lv[32 * 136];   // [32 dims][128+8 pad] bf16
  const int tid = threadIdx.x;
  const int lane = tid & 63;
  const int w = tid >> 6;
  const int kl = lane & 31;
  const int hi = lane >> 5;
  const int h = blockIdx.y, hc = h * HDIM;
  const int q = blockIdx.x * 128 + w * 32 + kl;
  const int ks0 = blockIdx.z * 512;

  short8 qf0 = *(const short8*)&Qb[q * DIM + hc + hi * 8];
  short8 qf1 = *(const short8*)&Qb[q * DIM + hc + 16 + hi * 8];

  f32x16 zc;                      // loop-invariant zero C-operand (hoisted out of subs)
#pragma unroll
  for (int r = 0; r < 16; ++r) zc[r] = 0.f;
  f32x16 o = zc;
  float lsum = 0.f;

  for (int t = 0; t < 4; ++t) {
    const int kb = ks0 + t * 128;
    short8 kreg0, kreg1, vreg0, vreg1;
    {
      int key = tid >> 2, slot = tid & 3;
      kreg0 = *(const short8*)&K2b[(kb + key) * DIM + hc + slot * 8];
      kreg1 = *(const short8*)&K2b[(kb + 64 + key) * DIM + hc + slot * 8];
      int dim = tid >> 3, s2 = tid & 7;
      vreg0 = *(const short8*)&Vtb[(hc + dim) * NN + kb + s2 * 8];
      vreg1 = *(const short8*)&Vtb[(hc + dim) * NN + kb + 64 + s2 * 8];
    }
    __syncthreads();
    {
      int key = tid >> 2, slot = tid & 3;
      *(short8*)&lk[key * 40 + slot * 8] = kreg0;
      *(short8*)&lk[(64 + key) * 40 + slot * 8] = kreg1;
      int dim = tid >> 3, s2 = tid & 7;
      *(short8*)&lv[dim * 136 + s2 * 8] = vreg0;
      *(short8*)&lv[dim * 136 + 64 + s2 * 8] = vreg1;
    }
    __syncthreads();

#pragma unroll
    for (int sub = 0; sub < 4; ++sub) {
      const int base = sub * 32;
      short8 a0 = *(const short8*)&lk[(base + kl) * 40 + hi * 8];
      short8 a1 = *(const short8*)&lk[(base + kl) * 40 + 16 + hi * 8];
      f32x16 c = __builtin_amdgcn_mfma_f32_32x32x16_bf16(a0, qf0, zc, 0, 0, 0);
      c = __builtin_amdgcn_mfma_f32_32x32x16_bf16(a1, qf1, c, 0, 0, 0);
      float p[16];
#pragma unroll
      for (int r = 0; r < 16; ++r) p[r] = EXP2(c[r]);
      {  // tree-sum (short dep chain)
        float t0 = (p[0] + p[1]) + (p[2] + p[3]);
        float t1 = (p[4] + p[5]) + (p[6] + p[7]);
        float t2 = (p[8] + p[9]) + (p[10] + p[11]);
        float t3 = (p[12] + p[13]) + (p[14] + p[15]);
        lsum += (t0 + t1) + (t2 + t3);
      }
      unsigned X0 = pk_bf16(p[0], p[1]);
      unsigned Y0 = pk_bf16(p[2], p[3]);
      unsigned Z0 = pk_bf16(p[4], p[5]);
      unsigned W0 = pk_bf16(p[6], p[7]);
      asm volatile("v_permlane32_swap_b32 %0, %1" : "+v"(X0), "+v"(Z0));
      asm volatile("v_permlane32_swap_b32 %0, %1" : "+v"(Y0), "+v"(W0));
      unsigned X1 = pk_bf16(p[8], p[9]);
      unsigned Y1 = pk_bf16(p[10], p[11]);
      unsigned Z1 = pk_bf16(p[12], p[13]);
      unsigned W1 = pk_bf16(p[14], p[15]);
      asm volatile("v_permlane32_swap_b32 %0, %1" : "+v"(X1), "+v"(Z1));
      asm volatile("v_permlane32_swap_b32 %0, %1" : "+v"(Y1), "+v"(W1));
      short8 pb0, pb1;
      ((unsigned*)&pb0)[0] = X0; ((unsigned*)&pb0)[1] = Y0;
      ((unsigned*)&pb0)[2] = Z0; ((unsigned*)&pb0)[3] = W0;
      ((unsigned*)&pb1)[0] = X1; ((unsigned*)&pb1)[1] = Y1;
      ((unsigned*)&pb1)[2] = Z1; ((unsigned*)&pb1)[3] = W1;
      short8 va0 = *(const short8*)&lv[kl * 136 + base + hi * 8];
      short8 va1 = *(const short8*)&lv[kl * 136 + base + 16 + hi * 8];
      o = __builtin_amdgcn_mfma_f32_32x32x16_bf16(va0, pb0, o, 0, 0, 0);
      o = __builtin_amdgcn_mfma_f32_32x32x16_bf16(va1, pb1, o, 0, 0, 0);
    }
  }

  float lt = lsum + __shfl_xor(lsum, 32);
  unsigned short* OTz = OT + blockIdx.z * NM;
#pragma unroll
  for (int r = 0; r < 16; ++r) {
    int d = (r & 3) + 8 * (r >> 2) + 4 * hi;
    OTz[(hc + d) * NN + q] = (unsigned short)bfbits(o[r]);
  }
  if (hi == 0) Lp[(blockIdx.z * 8 + h) * NN + q] = lt;
}

// ---------------- merge: H = inp + (sum_z OT_z)^T / (sum_z Lp_z); emits f32 + bf16 ------
__global__ __launch_bounds__(256) void merge_h(
    const float* __restrict__ inp, const unsigned short* __restrict__ OT,
    const float* __restrict__ Lp, float* __restrict__ Hf,
    unsigned short* __restrict__ Hbf) {
  __shared__ float ls[32][132];
  __shared__ float linv[128];
  const int tid = threadIdx.x;
  const int qb = blockIdx.x * 128;
  const int h = blockIdx.y, hc = h * HDIM;

#pragma unroll
  for (int pass = 0; pass < 4; ++pass) {
    int d = (tid >> 5) + pass * 8;
    int q4 = (tid & 31) * 4;
    float a0 = 0, a1 = 0, a2 = 0, a3 = 0;
#pragma unroll
    for (int z = 0; z < 8; ++z) {
      ushort4 v = *(const ushort4*)&OT[z * NM + (hc + d) * NN + qb + q4];
      a0 += bf2f(v.x); a1 += bf2f(v.y); a2 += bf2f(v.z); a3 += bf2f(v.w);
    }
    ls[d][q4 + 0] = a0; ls[d][q4 + 1] = a1;
    ls[d][q4 + 2] = a2; ls[d][q4 + 3] = a3;
  }
  if (tid < 128) {
    int q = qb + tid;
    float s = 0;
#pragma unroll
    for (int z = 0; z < 8; ++z) s += Lp[(z * 8 + h) * NN + q];
    linv[tid] = 1.f / s;
  }
  __syncthreads();
#pragma unroll
  for (int pass = 0; pass < 4; ++pass) {
    int q = (tid >> 3) + pass * 32;
    int dg = (tid & 7) * 4;
    float iv = linv[q];
    float4 in4 = *(const float4*)&inp[(qb + q) * DIM + hc + dg];
    float r0 = in4.x + ls[dg + 0][q] * iv;
    float r1 = in4.y + ls[dg + 1][q] * iv;
    float r2 = in4.z + ls[dg + 2][q] * iv;
    float r3 = in4.w + ls[dg + 3][q] * iv;
    *(float4*)&Hf[(qb + q) * DIM + hc + dg] = make_float4(r0, r1, r2, r3);
    ushort4 hb;
    hb.x = bfbits(r0); hb.y = bfbits(r1); hb.z = bfbits(r2); hb.w = bfbits(r3);
    *(ushort4*)&Hbf[(qb + q) * DIM + hc + dg] = hb;
  }
}

// ---------------- final GEMM (bf16 MFMA): out = Hf + leaky(Hbf @ Wc + bc) ----------------
__global__ __launch_bounds__(256) void gemm_final_mfma(
    const unsigned short* __restrict__ Hbf, const unsigned short* __restrict__ Wct,
    const float* __restrict__ Hf, const float* __restrict__ bc,
    float* __restrict__ out) {
  __shared__ __align__(16) short sA[64 * 256];
  __shared__ __align__(16) short sB[64 * 256];
  const int tid = threadIdx.x;
  const int m0 = blockIdx.x * 64;
  const int n0 = blockIdx.y * 64;
  // full-K staging: 64 rows x 32 slots x 16B (r4 BUG: was 16 slots = half K)
#pragma unroll
  for (int i = 0; i < 8; ++i) {
    int idx = i * 256 + tid;                 // [0,2048)
    int row = idx >> 5, slot = idx & 31;
    short8 v = *(const short8*)&Hbf[(m0 + row) * DIM + slot * 8];
    int byte = (slot * 16) ^ ((row & 15) << 4);
    *(short8*)((char*)sA + row * 512 + byte) = v;
  }
#pragma unroll
  for (int i = 0; i < 8; ++i) {
    int idx = i * 256 + tid;
    int row = idx >> 5, slot = idx & 31;
    short8 v = *(const short8*)&Wct[(n0 + row) * DIM + slot * 8];
    int byte = (slot * 16) ^ ((row & 15) << 4);
    *(short8*)((char*)sB + row * 512 + byte) = v;
  }
  __syncthreads();
  const int kl = tid & 31, hi = (tid & 63) >> 5, w = tid >> 6;
  const int rw = (w >> 1) * 32, cw = (w & 1) * 32;
  const int arow = rw + kl, brow = cw + kl;
  const int axor = (arow & 15) << 4, bxor = (brow & 15) << 4;
  const char* apA = (const char*)sA + arow * 512;
  const char* apB = (const char*)sB + brow * 512;
  f32x16 acc;
#pragma unroll
  for (int r = 0; r < 16; ++r) acc[r] = 0.f;
#pragma unroll
  for (int ks = 0; ks < 16; ++ks) {
    int cb = ks * 32 + hi * 16;
    short8 a = *(const short8*)(apA + (cb ^ axor));
    short8 b = *(const short8*)(apB + (cb ^ bxor));
    acc = __builtin_amdgcn_mfma_f32_32x32x16_bf16(a, b, acc, 0, 0, 0);
  }
#pragma unroll
  for (int r = 0; r < 16; ++r) {
    int mrow = (r & 3) + 8 * (r >> 2) + 4 * hi;
    int node = m0 + rw + mrow, col = n0 + cw + kl;
    float x = acc[r] + bc[col];
    x = x > 0.f ? x : LEAKY * x;
    out[node * DIM + col] = Hf[node * DIM + col] + x;
  }
}

extern "C" void kernel_launch(void* const* d_in, const int* in_sizes, int n_in,
                              void* d_out, int out_size, void* d_ws, size_t ws_size,
                              hipStream_t stream) {
  const float* inp = (const float*)d_in[0];
  const int* src   = (const int*)d_in[1];
  const int* dst   = (const int*)d_in[2];
  const float* WQ  = (const float*)d_in[3];
  const float* WK  = (const float*)d_in[4];
  const float* WV  = (const float*)d_in[5];
  const float* Wc  = (const float*)d_in[6];
  const float* bc  = (const float*)d_in[7];
  float* out = (float*)d_out;
  const int E = in_sizes[1];

  // ws layout (~25.6 MB), with lifetime-based overlaps:
  //  Qb   @0      2MB  (dead after attn)      -> Hbf reuses @0
  //  Kb   @2M     2MB
  //  Vtb  @4M     2MB  (dead after attn)  \ -> Hf (4MB) reuses @4M
  //  K2b  @6M     2MB  (dead after attn)  /
  //  Wtb  @8M     512KB (4 x 256x256 bf16, transposed; PREF in WQ)
  //  OT   @8.5M   16MB bf16 (8 x [256][4096]); Vb (2MB) overlaps @8.5M (dead pre-attn)
  //  Lp   @24.5M  512KB
  //  csr  @25M    ~0.6MB
  char* ws = (char*)d_ws;
  unsigned short* Qb  = (unsigned short*)(ws);
  unsigned short* Kb  = (unsigned short*)(ws + 2  * 1024 * 1024);
  unsigned short* Vtb = (unsigned short*)(ws + 4  * 1024 * 1024);
  unsigned short* K2b = (unsigned short*)(ws + 6  * 1024 * 1024);
  unsigned short* Wtb = (unsigned short*)(ws + 8  * 1024 * 1024);
  unsigned short* OT  = (unsigned short*)(ws + 8 * 1024 * 1024 + 524288);
  unsigned short* Vb  = OT;                                   // overlap: dead before attn
  float* Lp           = (float*)(ws + 24 * 1024 * 1024 + 524288);
  char* csr           = ws + 25 * 1024 * 1024;
  int* cnt            = (int*)(csr);
  int* ofs            = (int*)(csr + 16384);
  int* cur            = (int*)(csr + 36864);
  int* esrc           = (int*)(csr + 53248);
  unsigned short* Hbf = Qb;                                   // overlap: Qb dead after attn
  float* Hf           = (float*)(ws + 4 * 1024 * 1024);       // overlap: Vtb+K2b dead

  zero_i32<<<16, 256, 0, stream>>>(cnt, NN);
  convert_w<<<dim3(16, 4), 256, 0, stream>>>(WQ, WK, WV, Wc, Wtb);
  gemm_qkv_mfma<<<dim3(64, 4, 3), 256, 0, stream>>>(inp, Wtb, Qb, Kb, Vb);
  hist_dst<<<(E + 255) / 256, 256, 0, stream>>>(dst, cnt, E);
  scan4096<<<1, 256, 0, stream>>>(cnt, ofs, cur);
  fill_edges<<<(E + 255) / 256, 256, 0, stream>>>(src, dst, cur, esrc, E);
  gather_k2<<<NN / 4, 256, 0, stream>>>(Kb, ofs, esrc, K2b);
  transpose_v<<<dim3(64, 4), 256, 0, stream>>>(Vb, Vtb);
  attn_mfma<<<dim3(32, 8, 8), 256, 0, stream>>>(Qb, K2b, Vtb, OT, Lp);
  merge_h<<<dim3(32, 8), 256, 0, stream>>>(inp, OT, Lp, Hf, Hbf);
  gemm_final_mfma<<<dim3(64, 4), 256, 0, stream>>>(Hbf, Wtb + 3 * 65536, Hf, bc, out);
}

// Round 6
// 101.461 us; speedup vs baseline: 9.8606x; 1.0918x over previous
//
#include <hip/hip_runtime.h>
#include <hip/hip_bf16.h>
#include <math.h>

#define DIM 256
#define HDIM 32
#define NN 4096
#define NM (NN * DIM)
// (1/sqrt(256)) * log2(e) -- folded into WQ so scores are in exp2 domain
#define PREF 0.09016844005555896f
#define LEAKY 0.2f

typedef __attribute__((ext_vector_type(8))) short short8;
typedef __attribute__((ext_vector_type(16))) float f32x16;

#if __has_builtin(__builtin_amdgcn_exp2f)
#define EXP2(x) __builtin_amdgcn_exp2f(x)   // raw v_exp_f32: scores bounded, no fixups needed
#else
#define EXP2(x) exp2f(x)
#endif

static __device__ __forceinline__ unsigned bfbits(float x) {
  unsigned u = __float_as_uint(x);
  return (u + 0x7fffu + ((u >> 16) & 1u)) >> 16;   // RNE f32->bf16 bits
}
static __device__ __forceinline__ float bf2f(unsigned short b) {
  return __uint_as_float(((unsigned)b) << 16);
}
static __device__ __forceinline__ unsigned pk_bf16(float lo, float hi) {
  __hip_bfloat162 t = __float22bfloat162_rn(make_float2(lo, hi));  // v_cvt_pk_bf16_f32
  return *(unsigned*)&t;
}

// ---- convert: Wtb[w][n][k] = bf16(W_w[k][n]*scale); y==4: Ab = bf16(inp), x==0 zeros cnt
// grid (64, 5); w-convert uses x<16 only.
__global__ __launch_bounds__(256) void convert_w(
    const float* __restrict__ W0, const float* __restrict__ W1,
    const float* __restrict__ W2, const float* __restrict__ W3,
    const float* __restrict__ inp, unsigned short* __restrict__ Wtb,
    unsigned short* __restrict__ Ab, int* __restrict__ cnt) {
  const int tid = threadIdx.x;
  if (blockIdx.y == 4) {
    // inp f32 -> bf16: 64 blocks x 256 th x 16 float4
#pragma unroll
    for (int i = 0; i < 16; ++i) {
      int idx = (blockIdx.x * 4096 + i * 256 + tid) * 4;
      float4 v = *(const float4*)&inp[idx];
      *(uint2*)&Ab[idx] = make_uint2(pk_bf16(v.x, v.y), pk_bf16(v.z, v.w));
    }
    if (blockIdx.x == 0) {
#pragma unroll
      for (int i = 0; i < 16; ++i) cnt[i * 256 + tid] = 0;
    }
    return;
  }
  if (blockIdx.x >= 16) return;
  __shared__ float tile[64][68];
  const int wsel = blockIdx.y;
  const float* W = wsel == 0 ? W0 : (wsel == 1 ? W1 : (wsel == 2 ? W2 : W3));
  const float scale = wsel == 0 ? PREF : 1.f;
  const int kb = (blockIdx.x & 3) * 64, nb = (blockIdx.x >> 2) * 64;
#pragma unroll
  for (int i = 0; i < 4; ++i) {
    int idx = i * 256 + tid;                 // [0,1024)
    int kr = idx >> 4, ns = idx & 15;
    float4 v = *(const float4*)&W[(kb + kr) * DIM + nb + ns * 4];
    tile[kr][ns * 4 + 0] = v.x; tile[kr][ns * 4 + 1] = v.y;
    tile[kr][ns * 4 + 2] = v.z; tile[kr][ns * 4 + 3] = v.w;
  }
  __syncthreads();
  unsigned short* o = Wtb + wsel * 65536;
#pragma unroll
  for (int i = 0; i < 2; ++i) {
    int idx = i * 256 + tid;                 // [0,512) = 64 n-rows x 8 kslots
    int nr = idx >> 3, kslot = idx & 7;
    short8 v;
#pragma unroll
    for (int j = 0; j < 8; ++j)
      ((unsigned short*)&v)[j] = (unsigned short)bfbits(tile[kslot * 8 + j][nr] * scale);
    *(short8*)&o[(nb + nr) * DIM + kb + kslot * 8] = v;
  }
}

// ---------------- QKV GEMM (bf16 MFMA 32x32x16): C = Ab @ W, out bf16 row-major ----------
// grid (64 mtiles, 4 ntiles, 3 wsel). Block 256 = 4 waves in 2x2 over 64x64 tile.
// LDS rows 512B (=256 bf16, full K), XOR-swizzle byte ^= ((row&15)<<4).
__global__ __launch_bounds__(256) void gemm_qkv_mfma(
    const unsigned short* __restrict__ Ab, const unsigned short* __restrict__ Wtb,
    unsigned short* __restrict__ Qb, unsigned short* __restrict__ Kb,
    unsigned short* __restrict__ Vb) {
  __shared__ __align__(16) short sA[64 * 256];   // 32 KB
  __shared__ __align__(16) short sB[64 * 256];   // 32 KB
  const int tid = threadIdx.x;
  const int m0 = blockIdx.x * 64;
  const int n0 = blockIdx.y * 64;
  const int wsel = blockIdx.z;
  const unsigned short* Wt = Wtb + wsel * 65536;
  // full-K staging: 64 rows x 32 slots x 16B each (coverage audited: 2048 writes = 64x512B)
#pragma unroll
  for (int i = 0; i < 8; ++i) {
    int idx = i * 256 + tid;                 // [0,2048)
    int row = idx >> 5, slot = idx & 31;
    short8 v = *(const short8*)&Ab[(m0 + row) * DIM + slot * 8];
    int byte = (slot * 16) ^ ((row & 15) << 4);
    *(short8*)((char*)sA + row * 512 + byte) = v;
  }
#pragma unroll
  for (int i = 0; i < 8; ++i) {
    int idx = i * 256 + tid;
    int row = idx >> 5, slot = idx & 31;
    short8 v = *(const short8*)&Wt[(n0 + row) * DIM + slot * 8];
    int byte = (slot * 16) ^ ((row & 15) << 4);
    *(short8*)((char*)sB + row * 512 + byte) = v;
  }
  __syncthreads();
  const int kl = tid & 31, hi = (tid & 63) >> 5, w = tid >> 6;
  const int rw = (w >> 1) * 32, cw = (w & 1) * 32;
  const int arow = rw + kl, brow = cw + kl;
  const int axor = (arow & 15) << 4, bxor = (brow & 15) << 4;
  const char* apA = (const char*)sA + arow * 512;
  const char* apB = (const char*)sB + brow * 512;
  f32x16 acc;
#pragma unroll
  for (int r = 0; r < 16; ++r) acc[r] = 0.f;
#pragma unroll
  for (int ks = 0; ks < 16; ++ks) {
    int cb = ks * 32 + hi * 16;
    short8 a = *(const short8*)(apA + (cb ^ axor));
    short8 b = *(const short8*)(apB + (cb ^ bxor));
    acc = __builtin_amdgcn_mfma_f32_32x32x16_bf16(a, b, acc, 0, 0, 0);
  }
  unsigned short* C = wsel == 0 ? Qb : (wsel == 1 ? Kb : Vb);
#pragma unroll
  for (int r = 0; r < 16; ++r) {
    int mrow = (r & 3) + 8 * (r >> 2) + 4 * hi;
    C[(m0 + rw + mrow) * DIM + n0 + cw + kl] = (unsigned short)bfbits(acc[r]);
  }
}

// ---------------- CSR build: histogram, scan, fill ----------------
__global__ void hist_dst(const int* __restrict__ dst, int* __restrict__ cnt, int E) {
  int e = blockIdx.x * 256 + threadIdx.x;
  if (e < E) atomicAdd(&cnt[dst[e]], 1);
}

__global__ void scan4096(const int* __restrict__ cnt, int* __restrict__ ofs,
                         int* __restrict__ cur) {
  __shared__ int ps[256];
  int t = threadIdx.x;
  int loc[16]; int s = 0;
#pragma unroll
  for (int i = 0; i < 16; ++i) { loc[i] = s; s += cnt[t * 16 + i]; }
  ps[t] = s;
  __syncthreads();
  for (int o = 1; o < 256; o <<= 1) {
    int v = ps[t];
    int u = (t >= o) ? ps[t - o] : 0;
    __syncthreads();
    ps[t] = v + u;
    __syncthreads();
  }
  int base = (t == 0) ? 0 : ps[t - 1];
#pragma unroll
  for (int i = 0; i < 16; ++i) {
    int v = base + loc[i];
    ofs[t * 16 + i] = v; cur[t * 16 + i] = v;
  }
  if (t == 255) ofs[4096] = ps[255];
}

__global__ void fill_edges(const int* __restrict__ src, const int* __restrict__ dst,
                           int* __restrict__ cur, int* __restrict__ esrc, int E) {
  int e = blockIdx.x * 256 + threadIdx.x;
  if (e < E) {
    int p = atomicAdd(&cur[dst[e]], 1);
    esrc[p] = src[e];
  }
}

// ---- fused gather (blocks 0..1023) + V transpose (blocks 1024..1279) ----
__global__ __launch_bounds__(256) void gather_transpose(
    const unsigned short* __restrict__ Kb, const int* __restrict__ ofs,
    const int* __restrict__ esrc, unsigned short* __restrict__ K2b,
    const unsigned short* __restrict__ Vb, unsigned short* __restrict__ Vtb) {
  const int tid = threadIdx.x;
  if (blockIdx.x < 1024) {       // gather: wave per dst node, K2b[d] = sum K[src]
    int w = tid >> 6, lane = tid & 63;
    int d = blockIdx.x * 4 + w;
    int beg = ofs[d], end = ofs[d + 1];
    float a0 = 0, a1 = 0, a2 = 0, a3 = 0;
    for (int j = beg; j < end; ++j) {
      int s = esrc[j];
      ushort4 kv = *(const ushort4*)&Kb[s * DIM + lane * 4];
      a0 += bf2f(kv.x); a1 += bf2f(kv.y); a2 += bf2f(kv.z); a3 += bf2f(kv.w);
    }
    ushort4 o;
    o.x = bfbits(a0); o.y = bfbits(a1); o.z = bfbits(a2); o.w = bfbits(a3);
    *(ushort4*)&K2b[d * DIM + lane * 4] = o;
    return;
  }
  // transpose: Vtb[dim][node] = Vb[node][dim], 64x64 tiles
  __shared__ __align__(16) unsigned short tile[64][72];
  const int b = blockIdx.x - 1024;
  const int nb = (b & 63) * 64;
  const int db = (b >> 6) * 64;
#pragma unroll
  for (int i = 0; i < 2; ++i) {
    int idx = i * 256 + tid;                 // [0,512) = 64 nodes x 8 slots
    int row = idx >> 3, slot = idx & 7;
    short8 v = *(const short8*)&Vb[(nb + row) * DIM + db + slot * 8];
    *(short8*)&tile[row][slot * 8] = v;
  }
  __syncthreads();
#pragma unroll
  for (int i = 0; i < 2; ++i) {
    int idx = i * 256 + tid;
    int drow = idx >> 3, nslot = idx & 7;
    short8 v;
#pragma unroll
    for (int j = 0; j < 8; ++j) ((unsigned short*)&v)[j] = tile[nslot * 8 + j][drow];
    *(short8*)&Vtb[(db + drow) * NN + nb + nslot * 8] = v;
  }
}

// ---------------- fused MFMA flash attention + merge (bf16, 32x32x16) ----------------
// grid (64 q-blocks, 8 heads); block 512 = 8 waves = 2 q-waves x 4 z-groups.
// Wave owns 32 q rows; z-group zg owns keys [zg*1024, zg*1024+1024), own LDS K/V tiles.
// Swapped form: S^T = mfma(A=K2, B=Q); P via cvt_pk + permlane32_swap; O^T = mfma(V^T, P^T).
// In-block merge through LDS (aliased over K/V tiles) -> H = inp + attn, f32 + bf16 out.
__global__ __launch_bounds__(512, 4) void attn_fused(
    const unsigned short* __restrict__ Qb, const unsigned short* __restrict__ K2b,
    const unsigned short* __restrict__ Vtb, const float* __restrict__ inp,
    float* __restrict__ Hf, unsigned short* __restrict__ Hbf) {
  __shared__ __align__(16) char smem[75776];     // lk[4][128*40]s | lv[4][32*136]s; merge alias
  __shared__ float lbuf[4][64];
  const int tid = threadIdx.x;
  const int lane = tid & 63;
  const int wid = tid >> 6;
  const int qw = wid & 1;        // q-wave within block
  const int zg = wid >> 1;       // key-split group
  const int kl = lane & 31;
  const int hi = lane >> 5;
  const int gtid = tid & 127;    // thread id within z-group (2 waves)
  const int h = blockIdx.y, hc = h * HDIM;
  const int q_local = qw * 32 + kl;
  const int q = blockIdx.x * 64 + q_local;
  const int ks0 = zg * 1024;

  short* lk = (short*)smem + zg * 5120;            // [128][40]
  short* lv = (short*)(smem + 40960) + zg * 4352;  // [32][136]

  short8 qf0 = *(const short8*)&Qb[q * DIM + hc + hi * 8];
  short8 qf1 = *(const short8*)&Qb[q * DIM + hc + 16 + hi * 8];

  f32x16 zc;
#pragma unroll
  for (int r = 0; r < 16; ++r) zc[r] = 0.f;
  f32x16 o = zc;
  float lsum = 0.f;

  for (int t = 0; t < 8; ++t) {
    const int kb = ks0 + t * 128;
    short8 kreg[4], vreg[4];
    {
      int key = gtid >> 2, slot = gtid & 3;        // 4 passes x 32 keys
#pragma unroll
      for (int p = 0; p < 4; ++p)
        kreg[p] = *(const short8*)&K2b[(kb + key + p * 32) * DIM + hc + slot * 8];
      int dim = gtid >> 4, s2 = gtid & 15;         // 4 passes x 8 dims
#pragma unroll
      for (int p = 0; p < 4; ++p)
        vreg[p] = *(const short8*)&Vtb[(hc + dim + p * 8) * NN + kb + s2 * 8];
    }
    __syncthreads();
    {
      int key = gtid >> 2, slot = gtid & 3;
#pragma unroll
      for (int p = 0; p < 4; ++p)
        *(short8*)&lk[(key + p * 32) * 40 + slot * 8] = kreg[p];
      int dim = gtid >> 4, s2 = gtid & 15;
#pragma unroll
      for (int p = 0; p < 4; ++p)
        *(short8*)&lv[(dim + p * 8) * 136 + s2 * 8] = vreg[p];
    }
    __syncthreads();

#pragma unroll
    for (int sub = 0; sub < 4; ++sub) {
      const int base = sub * 32;
      short8 a0 = *(const short8*)&lk[(base + kl) * 40 + hi * 8];
      short8 a1 = *(const short8*)&lk[(base + kl) * 40 + 16 + hi * 8];
      f32x16 c = __builtin_amdgcn_mfma_f32_32x32x16_bf16(a0, qf0, zc, 0, 0, 0);
      c = __builtin_amdgcn_mfma_f32_32x32x16_bf16(a1, qf1, c, 0, 0, 0);
      float p[16];
#pragma unroll
      for (int r = 0; r < 16; ++r) p[r] = EXP2(c[r]);
      {
        float t0 = (p[0] + p[1]) + (p[2] + p[3]);
        float t1 = (p[4] + p[5]) + (p[6] + p[7]);
        float t2 = (p[8] + p[9]) + (p[10] + p[11]);
        float t3 = (p[12] + p[13]) + (p[14] + p[15]);
        lsum += (t0 + t1) + (t2 + t3);
      }
      unsigned X0 = pk_bf16(p[0], p[1]);
      unsigned Y0 = pk_bf16(p[2], p[3]);
      unsigned Z0 = pk_bf16(p[4], p[5]);
      unsigned W0 = pk_bf16(p[6], p[7]);
      asm volatile("v_permlane32_swap_b32 %0, %1" : "+v"(X0), "+v"(Z0));
      asm volatile("v_permlane32_swap_b32 %0, %1" : "+v"(Y0), "+v"(W0));
      unsigned X1 = pk_bf16(p[8], p[9]);
      unsigned Y1 = pk_bf16(p[10], p[11]);
      unsigned Z1 = pk_bf16(p[12], p[13]);
      unsigned W1 = pk_bf16(p[14], p[15]);
      asm volatile("v_permlane32_swap_b32 %0, %1" : "+v"(X1), "+v"(Z1));
      asm volatile("v_permlane32_swap_b32 %0, %1" : "+v"(Y1), "+v"(W1));
      short8 pb0, pb1;
      ((unsigned*)&pb0)[0] = X0; ((unsigned*)&pb0)[1] = Y0;
      ((unsigned*)&pb0)[2] = Z0; ((unsigned*)&pb0)[3] = W0;
      ((unsigned*)&pb1)[0] = X1; ((unsigned*)&pb1)[1] = Y1;
      ((unsigned*)&pb1)[2] = Z1; ((unsigned*)&pb1)[3] = W1;
      short8 va0 = *(const short8*)&lv[kl * 136 + base + hi * 8];
      short8 va1 = *(const short8*)&lv[kl * 136 + base + 16 + hi * 8];
      o = __builtin_amdgcn_mfma_f32_32x32x16_bf16(va0, pb0, o, 0, 0, 0);
      o = __builtin_amdgcn_mfma_f32_32x32x16_bf16(va1, pb1, o, 0, 0, 0);
    }
  }

  // in-block merge: o-frags + lsum partials through LDS (aliased over dead K/V tiles)
  float lt = lsum + __shfl_xor(lsum, 32);
  __syncthreads();
  float* mz = (float*)smem + zg * 2208;            // [32 dims][69 q] per group
#pragma unroll
  for (int r = 0; r < 16; ++r) {
    int d = (r & 3) + 8 * (r >> 2) + 4 * hi;
    mz[d * 69 + q_local] = o[r];                   // lanes q-consecutive: conflict-free
  }
  if (hi == 0) lbuf[zg][q_local] = lt;
  __syncthreads();
  {
    int ql = tid >> 3;                             // [0,64)
    int dg = (tid & 7) * 4;
    float s = (lbuf[0][ql] + lbuf[1][ql]) + (lbuf[2][ql] + lbuf[3][ql]);
    float inv = 1.f / s;
    const float* mb = (const float*)smem;
    float acc[4];
#pragma unroll
    for (int i = 0; i < 4; ++i) {
      int d = dg + i;
      acc[i] = (mb[d * 69 + ql] + mb[2208 + d * 69 + ql]) +
               (mb[4416 + d * 69 + ql] + mb[6624 + d * 69 + ql]);
    }
    int qg = blockIdx.x * 64 + ql;
    float4 in4 = *(const float4*)&inp[qg * DIM + hc + dg];
    float r0 = in4.x + acc[0] * inv;
    float r1 = in4.y + acc[1] * inv;
    float r2 = in4.z + acc[2] * inv;
    float r3 = in4.w + acc[3] * inv;
    *(float4*)&Hf[qg * DIM + hc + dg] = make_float4(r0, r1, r2, r3);
    ushort4 hb;
    hb.x = bfbits(r0); hb.y = bfbits(r1); hb.z = bfbits(r2); hb.w = bfbits(r3);
    *(ushort4*)&Hbf[qg * DIM + hc + dg] = hb;
  }
}

// ---------------- final GEMM (bf16 MFMA): out = Hf + leaky(Hbf @ Wc + bc) ----------------
__global__ __launch_bounds__(256) void gemm_final_mfma(
    const unsigned short* __restrict__ Hbf, const unsigned short* __restrict__ Wct,
    const float* __restrict__ Hf, const float* __restrict__ bc,
    float* __restrict__ out) {
  __shared__ __align__(16) short sA[64 * 256];
  __shared__ __align__(16) short sB[64 * 256];
  const int tid = threadIdx.x;
  const int m0 = blockIdx.x * 64;
  const int n0 = blockIdx.y * 64;
#pragma unroll
  for (int i = 0; i < 8; ++i) {
    int idx = i * 256 + tid;                 // [0,2048)
    int row = idx >> 5, slot = idx & 31;
    short8 v = *(const short8*)&Hbf[(m0 + row) * DIM + slot * 8];
    int byte = (slot * 16) ^ ((row & 15) << 4);
    *(short8*)((char*)sA + row * 512 + byte) = v;
  }
#pragma unroll
  for (int i = 0; i < 8; ++i) {
    int idx = i * 256 + tid;
    int row = idx >> 5, slot = idx & 31;
    short8 v = *(const short8*)&Wct[(n0 + row) * DIM + slot * 8];
    int byte = (slot * 16) ^ ((row & 15) << 4);
    *(short8*)((char*)sB + row * 512 + byte) = v;
  }
  __syncthreads();
  const int kl = tid & 31, hi = (tid & 63) >> 5, w = tid >> 6;
  const int rw = (w >> 1) * 32, cw = (w & 1) * 32;
  const int arow = rw + kl, brow = cw + kl;
  const int axor = (arow & 15) << 4, bxor = (brow & 15) << 4;
  const char* apA = (const char*)sA + arow * 512;
  const char* apB = (const char*)sB + brow * 512;
  f32x16 acc;
#pragma unroll
  for (int r = 0; r < 16; ++r) acc[r] = 0.f;
#pragma unroll
  for (int ks = 0; ks < 16; ++ks) {
    int cb = ks * 32 + hi * 16;
    short8 a = *(const short8*)(apA + (cb ^ axor));
    short8 b = *(const short8*)(apB + (cb ^ bxor));
    acc = __builtin_amdgcn_mfma_f32_32x32x16_bf16(a, b, acc, 0, 0, 0);
  }
#pragma unroll
  for (int r = 0; r < 16; ++r) {
    int mrow = (r & 3) + 8 * (r >> 2) + 4 * hi;
    int node = m0 + rw + mrow, col = n0 + cw + kl;
    float x = acc[r] + bc[col];
    x = x > 0.f ? x : LEAKY * x;
    out[node * DIM + col] = Hf[node * DIM + col] + x;
  }
}

extern "C" void kernel_launch(void* const* d_in, const int* in_sizes, int n_in,
                              void* d_out, int out_size, void* d_ws, size_t ws_size,
                              hipStream_t stream) {
  const float* inp = (const float*)d_in[0];
  const int* src   = (const int*)d_in[1];
  const int* dst   = (const int*)d_in[2];
  const float* WQ  = (const float*)d_in[3];
  const float* WK  = (const float*)d_in[4];
  const float* WV  = (const float*)d_in[5];
  const float* Wc  = (const float*)d_in[6];
  const float* bc  = (const float*)d_in[7];
  float* out = (float*)d_out;
  const int E = in_sizes[1];

  // ws layout (~19.2 MB, no lifetime overlaps needed):
  char* ws = (char*)d_ws;
  unsigned short* Ab  = (unsigned short*)(ws);                      // 2 MB bf16 inp
  unsigned short* Qb  = (unsigned short*)(ws + 2  * 1024 * 1024);   // 2 MB
  unsigned short* Kb  = (unsigned short*)(ws + 4  * 1024 * 1024);   // 2 MB
  unsigned short* Vb  = (unsigned short*)(ws + 6  * 1024 * 1024);   // 2 MB
  unsigned short* Vtb = (unsigned short*)(ws + 8  * 1024 * 1024);   // 2 MB
  unsigned short* K2b = (unsigned short*)(ws + 10 * 1024 * 1024);   // 2 MB
  unsigned short* Wtb = (unsigned short*)(ws + 12 * 1024 * 1024);   // 512 KB
  float* Hf           = (float*)(ws + 12 * 1024 * 1024 + 524288);   // 4 MB
  unsigned short* Hbf = (unsigned short*)(ws + 16 * 1024 * 1024 + 524288);  // 2 MB
  char* csr           = ws + 18 * 1024 * 1024 + 524288;
  int* cnt            = (int*)(csr);                // 16 KB
  int* ofs            = (int*)(csr + 16384);        // 4097 ints
  int* cur            = (int*)(csr + 36864);        // 16 KB
  int* esrc           = (int*)(csr + 53248);        // 512 KB

  convert_w<<<dim3(64, 5), 256, 0, stream>>>(WQ, WK, WV, Wc, inp, Wtb, Ab, cnt);
  gemm_qkv_mfma<<<dim3(64, 4, 3), 256, 0, stream>>>(Ab, Wtb, Qb, Kb, Vb);
  hist_dst<<<(E + 255) / 256, 256, 0, stream>>>(dst, cnt, E);
  scan4096<<<1, 256, 0, stream>>>(cnt, ofs, cur);
  fill_edges<<<(E + 255) / 256, 256, 0, stream>>>(src, dst, cur, esrc, E);
  gather_transpose<<<1280, 256, 0, stream>>>(Kb, ofs, esrc, K2b, Vb, Vtb);
  attn_fused<<<dim3(64, 8), 512, 0, stream>>>(Qb, K2b, Vtb, inp, Hf, Hbf);
  gemm_final_mfma<<<dim3(64, 4), 256, 0, stream>>>(Hbf, Wtb + 3 * 65536, Hf, bc, out);
}